// Round 8
// baseline (187.468 us; speedup 1.0000x reference)
//
#include <hip/hip_runtime.h>
#include <hip/hip_bf16.h>
#include <math.h>

#define N_PTS 32768
#define IN_F  256
#define NUM_CAT 16
#define CF    4096
#define NSEG  6
#define OUTK  50
#define BN_EPS 1e-5f

typedef unsigned short u16;
typedef __attribute__((ext_vector_type(8))) short bf16x8;
typedef __attribute__((ext_vector_type(4))) float f32x4;
typedef __attribute__((ext_vector_type(8))) unsigned short u16x8;

// ---- ws layout (float offsets) ----
#define OFF_G     0u          // 256*256
#define OFF_FBAR  65536u      // 256
#define OFF_SCALE 65792u      // 4096
#define OFF_SHIFT 69888u      // 4096
#define OFF_INT   73984u      // int region (33440 ints)
#define OFF_FB    107424u     // F bf16 [32768][256]
#define OFF_FBT   4301728u    // F^T bf16 [256][32768]
#define OFF_W1T   8496032u    // W1T bf16 [16][256 n][256 k]
#define OFF_GP    9020320u    // Gram partials [chunk][40960]
#define IO_COUNTS 0
#define IO_CATOFF 16
#define IO_TILEST 33
#define IO_NTILES 50
#define IO_CURSOR 51
#define IO_ORDER  67
#define IO_TILECAT 32835      // packed: c | (npts-1)<<4 | base<<11   (128-pt tiles)

__device__ __forceinline__ void gload_lds16(const void* g, void* l) {
    __builtin_amdgcn_global_load_lds(
        (const __attribute__((address_space(1))) void*)g,
        (__attribute__((address_space(3))) void*)l,
        16, 0, 0);
}
__device__ __forceinline__ u16 f2bf(float f) {
    unsigned int u = __float_as_uint(f);
    return (u16)((u + 0x7FFF + ((u >> 16) & 1)) >> 16);
}
__device__ __forceinline__ float bf2f(u16 h) {
    return __uint_as_float((unsigned int)h << 16);
}

// ============ K0: F -> Fb (row-major bf16) AND FbT (transposed bf16) ============
__global__ __launch_bounds__(256) void k0_cvt(const float* __restrict__ F,
                                              u16* __restrict__ Fb,
                                              u16* __restrict__ FbT) {
    const int pb = blockIdx.x >> 2, fb = blockIdx.x & 3;
    const int p0 = pb * 64, f0 = fb * 64;
    const int tid = threadIdx.x;
    __shared__ u16 T[64][72];
    {
        int p = tid >> 2, fq = tid & 3;
        const float* src = &F[(size_t)(p0 + p) * IN_F + f0 + fq * 16];
        u16x8 o0, o1;
        float4 v0 = *(const float4*)&src[0];
        float4 v1 = *(const float4*)&src[4];
        float4 v2 = *(const float4*)&src[8];
        float4 v3 = *(const float4*)&src[12];
        o0[0]=f2bf(v0.x); o0[1]=f2bf(v0.y); o0[2]=f2bf(v0.z); o0[3]=f2bf(v0.w);
        o0[4]=f2bf(v1.x); o0[5]=f2bf(v1.y); o0[6]=f2bf(v1.z); o0[7]=f2bf(v1.w);
        o1[0]=f2bf(v2.x); o1[1]=f2bf(v2.y); o1[2]=f2bf(v2.z); o1[3]=f2bf(v2.w);
        o1[4]=f2bf(v3.x); o1[5]=f2bf(v3.y); o1[6]=f2bf(v3.z); o1[7]=f2bf(v3.w);
        u16* dst = &Fb[(size_t)(p0 + p) * IN_F + f0 + fq * 16];
        *(u16x8*)dst = o0; *(u16x8*)&dst[8] = o1;
        *(u16x8*)&T[p][fq * 16] = o0; *(u16x8*)&T[p][fq * 16 + 8] = o1;
    }
    __syncthreads();
    {
        int f = tid >> 2, pq = tid & 3;
        u16x8 a0, a1;
#pragma unroll
        for (int m = 0; m < 8; m++) { a0[m] = T[pq*16 + m][f]; a1[m] = T[pq*16 + 8 + m][f]; }
        u16* dst = &FbT[(size_t)(f0 + f) * N_PTS + p0 + pq * 16];
        *(u16x8*)dst = a0; *(u16x8*)&dst[8] = a1;
    }
}

// ============ K0b: W1 [256][4096] -> W1T bf16 [c][n][k] ============
__global__ __launch_bounds__(256) void k0b_w1t(const float* __restrict__ W1,
                                               u16* __restrict__ W1T) {
    __shared__ u16 T[64][65];
    const int kb = blockIdx.x & 3, jb = blockIdx.x >> 2;
    const int tid = threadIdx.x;
    {
        int kk = tid >> 2, j4 = (tid & 3) * 16;
        const float* src = &W1[(size_t)(kb * 64 + kk) * CF + jb * 64 + j4];
#pragma unroll
        for (int q = 0; q < 4; q++) {
            float4 v = *(const float4*)&src[q * 4];
            T[kk][j4 + q * 4 + 0] = f2bf(v.x); T[kk][j4 + q * 4 + 1] = f2bf(v.y);
            T[kk][j4 + q * 4 + 2] = f2bf(v.z); T[kk][j4 + q * 4 + 3] = f2bf(v.w);
        }
    }
    __syncthreads();
    {
        int jj = tid >> 2, ks = (tid & 3) * 16;
        int c = jb >> 2, n = (jb & 3) * 64 + jj;
        u16* dst = &W1T[((size_t)(c * 256 + n)) * 256 + kb * 64 + ks];
        u16x8 o0, o1;
#pragma unroll
        for (int m = 0; m < 8; m++) { o0[m] = T[ks + m][jj]; o1[m] = T[ks + 8 + m][jj]; }
        *(u16x8*)dst = o0;
        *(u16x8*)&dst[8] = o1;
    }
}

// ============ K1: Gram via bf16 MFMA (10 symmetric tiles x nchunk K-chunks) ============
__global__ __launch_bounds__(256) void k1_gram(const u16* __restrict__ FbT,
                                               float* __restrict__ ws,
                                               int nchunk, int Kc) {
    const int TI[10] = {0,0,0,0,1,1,1,2,2,3};
    const int TJ[10] = {0,1,2,3,1,2,3,2,3,3};
    const int t = blockIdx.x % 10, chunk = blockIdx.x / 10;
    const int i0 = TI[t] * 64, j0 = TJ[t] * 64;
    const int r0 = chunk * Kc;
    const int tid = threadIdx.x;
    const int wv = tid >> 6, ln = tid & 63, g = ln >> 4, r16 = ln & 15;
    __shared__ __align__(16) u16 SA[2][4096];
    __shared__ __align__(16) u16 SB[2][4096];

    const int q0 = wv * 2, q1 = wv * 2 + 1;
    const int u_a = ((q0 * 64 + ln) & 7), row_a = (q0 * 64 + ln) >> 3;
    const int u_b = ((q1 * 64 + ln) & 7), row_b = (q1 * 64 + ln) >> 3;
    const int ka = ((u_a ^ (row_a & 7)) << 3), kb2 = ((u_b ^ (row_b & 7)) << 3);

    f32x4 acc[4];
#pragma unroll
    for (int nt = 0; nt < 4; nt++)
#pragma unroll
        for (int i = 0; i < 4; i++) acc[nt][i] = 0.f;

    const int nslab = Kc >> 6;
#define K1_STAGE(s, b)                                                              \
    {   int p0s = r0 + (s) * 64;                                                    \
        gload_lds16(FbT + (size_t)(i0 + row_a) * N_PTS + p0s + ka,                  \
                    (char*)SA[b] + q0 * 1024);                                      \
        gload_lds16(FbT + (size_t)(i0 + row_b) * N_PTS + p0s + kb2,                 \
                    (char*)SA[b] + q1 * 1024);                                      \
        gload_lds16(FbT + (size_t)(j0 + row_a) * N_PTS + p0s + ka,                  \
                    (char*)SB[b] + q0 * 1024);                                      \
        gload_lds16(FbT + (size_t)(j0 + row_b) * N_PTS + p0s + kb2,                 \
                    (char*)SB[b] + q1 * 1024);                                      \
    }

    K1_STAGE(0, 0);
    __syncthreads();
    for (int s = 0; s < nslab; s++) {
        const int b = s & 1;
        if (s + 1 < nslab) K1_STAGE(s + 1, b ^ 1);
#pragma unroll
        for (int ks = 0; ks < 2; ks++) {
            int ph = (ks * 4 + g) ^ (r16 & 7);
            bf16x8 a = *(const bf16x8*)((const char*)SA[b] + (wv * 16 + r16) * 128 + ph * 16);
#pragma unroll
            for (int nt = 0; nt < 4; nt++) {
                int nB = nt * 16 + r16;
                bf16x8 bb = *(const bf16x8*)((const char*)SB[b] + nB * 128 + ph * 16);
                acc[nt] = __builtin_amdgcn_mfma_f32_16x16x32_bf16(a, bb, acc[nt], 0, 0, 0);
            }
        }
        __syncthreads();
    }
    float* Gp = ws + OFF_GP + (size_t)chunk * 40960 + t * 4096;
#pragma unroll
    for (int nt = 0; nt < 4; nt++)
#pragma unroll
        for (int i = 0; i < 4; i++) {
            int row = wv * 16 + g * 4 + i, col = nt * 16 + r16;
            Gp[row * 64 + col] = acc[nt][i];
        }
}

// ============ K1b: column means from FbT; zero category counts ============
__global__ __launch_bounds__(256) void k1b_colsum(const u16* __restrict__ FbT,
                                                  float* __restrict__ ws) {
    const int row = blockIdx.x, tid = threadIdx.x;
    const u16* r = FbT + (size_t)row * N_PTS;
    float s = 0.f;
    for (int i = tid * 8; i < N_PTS; i += 2048) {
        u16x8 v = *(const u16x8*)&r[i];
#pragma unroll
        for (int m = 0; m < 8; m++) s += bf2f(v[m]);
    }
#pragma unroll
    for (int off = 32; off >= 1; off >>= 1) s += __shfl_xor(s, off);
    __shared__ float ps[4];
    if ((tid & 63) == 0) ps[tid >> 6] = s;
    __syncthreads();
    if (tid == 0) ws[OFF_FBAR + row] = (ps[0] + ps[1] + ps[2] + ps[3]) * (1.0f / N_PTS);
    if (blockIdx.x == 0 && tid < 16) ((int*)(ws + OFF_INT))[IO_COUNTS + tid] = 0;
}

// ============ K2a: coalesced reduce of Gram partials -> symmetric G ============
__global__ __launch_bounds__(256) void k2a_reduce(float* __restrict__ ws, int nchunk) {
    const int TI[10] = {0,0,0,0,1,1,1,2,2,3};
    const int TJ[10] = {0,1,2,3,1,2,3,2,3,3};
    const int e = blockIdx.x * 256 + threadIdx.x;   // 0..40959
    const float* p = ws + OFF_GP + e;
    float s = 0.f;
#pragma unroll 8
    for (int c = 0; c < nchunk; c++) s += p[(size_t)c * 40960];
    int t = e >> 12, x = (e >> 6) & 63, y = e & 63;
    int a = TI[t] * 64 + x, b = TJ[t] * 64 + y;
    ws[OFF_G + a * 256 + b] = s;
    ws[OFF_G + b * 256 + a] = s;
}

// ============ K2b: per-column mu/var -> scale/shift (32 cols/block) ============
__global__ __launch_bounds__(256) void k2b_stats(const float* __restrict__ W1,
                                                 const float* __restrict__ gamma,
                                                 const float* __restrict__ beta,
                                                 float* __restrict__ ws) {
    const int tid = threadIdx.x;
    const int j0 = blockIdx.x * 32;
    __shared__ __align__(16) float wl[32][256];
    __shared__ float pw[32][8];
#pragma unroll
    for (int q = 0; q < 8; q++) {
        float4 v = *(const float4*)&W1[(size_t)tid * CF + j0 + q * 4];
        wl[q * 4 + 0][tid] = v.x; wl[q * 4 + 1][tid] = v.y;
        wl[q * 4 + 2][tid] = v.z; wl[q * 4 + 3][tid] = v.w;
    }
    __syncthreads();
    float acc[32];
#pragma unroll
    for (int jj = 0; jj < 32; jj++) acc[jj] = 0.f;
    const float* G = ws + OFF_G;
    for (int b = 0; b < 256; b++) {
        float g = G[b * 256 + tid];
#pragma unroll
        for (int jj = 0; jj < 32; jj++) acc[jj] += g * wl[jj][b];
    }
    float fb = ws[OFF_FBAR + tid];
    const int lane = tid & 63, wave = tid >> 6;
#pragma unroll
    for (int jj = 0; jj < 32; jj++) {
        float v = wl[jj][tid] * acc[jj];
        float m = fb * wl[jj][tid];
#pragma unroll
        for (int off = 32; off >= 1; off >>= 1) {
            v += __shfl_xor(v, off);
            m += __shfl_xor(m, off);
        }
        if (lane == 0) { pw[jj][wave * 2] = v; pw[jj][wave * 2 + 1] = m; }
    }
    __syncthreads();
    if (tid < 32) {
        int jj = tid;
        float v = 0.f, m = 0.f;
        for (int w2 = 0; w2 < 4; w2++) { v += pw[jj][w2 * 2]; m += pw[jj][w2 * 2 + 1]; }
        float mu  = m;
        float var = v * (1.0f / N_PTS) - mu * mu;
        float sc  = gamma[j0 + jj] * rsqrtf(var + BN_EPS);
        float sh  = beta[j0 + jj] - mu * sc;
        ws[OFF_SCALE + j0 + jj] = sc;
        ws[OFF_SHIFT + j0 + jj] = sh;
    }
}

// ============ K3: category histogram ============
__global__ __launch_bounds__(256) void k3_hist(const int* __restrict__ cats,
                                               float* __restrict__ ws) {
    __shared__ int h[16];
    int tid = threadIdx.x;
    if (tid < 16) h[tid] = 0;
    __syncthreads();
    for (int n = blockIdx.x * 256 + tid; n < N_PTS; n += 64 * 256)
        atomicAdd(&h[cats[n]], 1);
    __syncthreads();
    int* wi = (int*)(ws + OFF_INT);
    if (tid < 16) atomicAdd(&wi[IO_COUNTS + tid], h[tid]);
}

// ============ K4: prefix sums + packed per-tile LUT (128-pt tiles) ============
__global__ void k4_prefix(float* __restrict__ ws) {
    int* wi = (int*)(ws + OFF_INT);
    if (threadIdx.x == 0) {
        int co = 0, ts = 0;
        wi[IO_CATOFF] = 0; wi[IO_TILEST] = 0;
        for (int c = 0; c < 16; c++) {
            int cnt = wi[IO_COUNTS + c];
            wi[IO_CURSOR + c] = co;
            int nt = (cnt + 127) >> 7;
            for (int lt = 0; lt < nt; lt++) {
                int npts = min(128, cnt - lt * 128);
                int b = co + lt * 128;
                wi[IO_TILECAT + ts + lt] = c | ((npts - 1) << 4) | (b << 11);
            }
            co += cnt; ts += nt;
            wi[IO_CATOFF + c + 1] = co;
            wi[IO_TILEST + c + 1] = ts;
        }
        wi[IO_NTILES] = ts;
    }
}

// ============ K4b: grouped scatter, two-level (block reservation + LDS ranks) ====
__global__ __launch_bounds__(256) void k4b_scatter(const int* __restrict__ cats,
                                                   float* __restrict__ ws) {
    int* wi = (int*)(ws + OFF_INT);
    __shared__ int lh[16], lbase[16];
    const int tid = threadIdx.x;
    const int n0 = blockIdx.x * 512;
    if (tid < 16) lh[tid] = 0;
    __syncthreads();
    const int cA = cats[n0 + tid];
    const int cB = cats[n0 + 256 + tid];
    atomicAdd(&lh[cA], 1);
    atomicAdd(&lh[cB], 1);
    __syncthreads();
    if (tid < 16) lbase[tid] = atomicAdd(&wi[IO_CURSOR + tid], lh[tid]);
    __syncthreads();
    if (tid < 16) lh[tid] = 0;
    __syncthreads();
    int rA = atomicAdd(&lh[cA], 1);
    wi[IO_ORDER + lbase[cA] + rA] = n0 + tid;
    int rB = atomicAdd(&lh[cB], 1);
    wi[IO_ORDER + lbase[cB] + rB] = n0 + 256 + tid;
}

// ============ K5: macro-block bf16-MFMA GEMM + fused epilogue ============
// Tile = (category, 128 points, all 256 cols). 512 threads / 8 waves.
// W1T category block (128 KB) staged into LDS ONCE per block (amortized over
// 128 points). 8 chunks of 16 points: F reg-prefetch -> ds_write -> 16 MFMA/wave
// -> BN+LeakyReLU+Wc partials in regs -> shfl reduce -> log-softmax + scatter.
__global__ __launch_bounds__(512) void k5_mfma(const u16* __restrict__ Fb,
                                               const u16* __restrict__ W1T,
                                               const float* __restrict__ Wc,
                                               const float* __restrict__ bias,
                                               const int* __restrict__ shifts,
                                               const int* __restrict__ seg_lens,
                                               const float* __restrict__ ws,
                                               float* __restrict__ out) {
    const int* wi = (const int*)(ws + OFF_INT);
    const int t = blockIdx.x;
    if (t >= wi[IO_NTILES]) return;
    const unsigned info = (unsigned)wi[IO_TILECAT + t];
    const int c    = info & 15;
    const int npts = ((info >> 4) & 127) + 1;
    const int base = info >> 11;
    const int tid = threadIdx.x;
    const int wv = tid >> 6, ln = tid & 63;
    const int g = ln >> 4, r16 = ln & 15;

    __shared__ __align__(16) u16 Wl[65536];       // 128 KB [256 n][512 B], 16B units ^(n&7)
    __shared__ __align__(16) u16 Fl[2][4096];     // 2 x 8 KB [16 pt][512 B], units ^(pt&7)
    __shared__ float red[16][8][6];
    __shared__ int plds[128];

    if (tid < 128) plds[tid] = wi[IO_ORDER + base + min(tid, npts - 1)];

    const u16* W1Tc = W1T + (size_t)c * 65536;
    // ---- stage full W block: 16 gload_lds per wave, linear dest, pre-swz src ----
#pragma unroll
    for (int i = 0; i < 16; i++) {
        int flat = i * 512 + tid;                 // 16B-unit index 0..8191
        int n = flat >> 5, u = flat & 31;
        const u16* src = W1Tc + (size_t)n * 256 + ((u ^ (n & 7)) << 3);
        gload_lds16(src, (char*)Wl + i * 8192 + wv * 1024);
    }

    // ---- per-thread column constants (cols wv*32 + {r16, r16+16}) ----
    const int col0 = wv * 32 + r16, col1 = col0 + 16;
    const float sc0 = ws[OFF_SCALE + c * 256 + col0];
    const float sc1 = ws[OFF_SCALE + c * 256 + col1];
    const float sh0 = ws[OFF_SHIFT + c * 256 + col0];
    const float sh1 = ws[OFF_SHIFT + c * 256 + col1];
    float wc0[6], wc1[6];
#pragma unroll
    for (int s = 0; s < 6; s++) {
        wc0[s] = Wc[(size_t)c * 1536 + col0 * 6 + s];
        wc1[s] = Wc[(size_t)c * 1536 + col1 * 6 + s];
    }
    const float biasj = ((tid & 7) < 6) ? bias[tid & 7] : 0.f;
    const int shc = shifts[c], lnc = seg_lens[c];

    __syncthreads();      // plds visible + W staged (vmcnt drained by barrier)

    // ---- F chunk prefetch: 512 threads x 16B cover 16 pts x 512 B ----
    const int fpt = tid >> 5, fu = tid & 31;
    u16x8 pf = *(const u16x8*)(Fb + (size_t)plds[fpt] * 256 + fu * 8);
    const int fdst = fpt * 256 + ((fu ^ (fpt & 7)) << 3);   // u16 offset, write-side swz
    const int r7 = r16 & 7;

    for (int ck = 0; ck < 8; ck++) {
        const int cur = ck & 1;
        *(u16x8*)(Fl[cur] + fdst) = pf;
        __syncthreads();                          // chunk data visible to all
        if (ck < 7)
            pf = *(const u16x8*)(Fb + (size_t)plds[(ck + 1) * 16 + fpt] * 256 + fu * 8);

        f32x4 acc0 = {0.f, 0.f, 0.f, 0.f}, acc1 = {0.f, 0.f, 0.f, 0.f};
#pragma unroll
        for (int kc = 0; kc < 8; kc++) {
            const int ph = ((kc * 4 + g) ^ r7) * 16;   // same phase for af/b0/b1
            bf16x8 af = *(const bf16x8*)((const char*)Fl[cur] + r16 * 512 + ph);
            bf16x8 b0 = *(const bf16x8*)((const char*)Wl + col0 * 512 + ph);
            bf16x8 b1 = *(const bf16x8*)((const char*)Wl + col1 * 512 + ph);
            acc0 = __builtin_amdgcn_mfma_f32_16x16x32_bf16(af, b0, acc0, 0, 0, 0);
            acc1 = __builtin_amdgcn_mfma_f32_16x16x32_bf16(af, b1, acc1, 0, 0, 0);
        }

        // ---- epilogue: BN + LeakyReLU + Wc partials, shfl-reduce over 16 lanes ----
        float pl[4][6];
#pragma unroll
        for (int i = 0; i < 4; i++) {
            float x0 = acc0[i] * sc0 + sh0;  x0 = (x0 >= 0.f) ? x0 : 0.2f * x0;
            float x1 = acc1[i] * sc1 + sh1;  x1 = (x1 >= 0.f) ? x1 : 0.2f * x1;
#pragma unroll
            for (int s = 0; s < 6; s++) pl[i][s] = x0 * wc0[s] + x1 * wc1[s];
        }
#pragma unroll
        for (int i = 0; i < 4; i++)
#pragma unroll
            for (int s = 0; s < 6; s++) {
                pl[i][s] += __shfl_xor(pl[i][s], 1);
                pl[i][s] += __shfl_xor(pl[i][s], 2);
                pl[i][s] += __shfl_xor(pl[i][s], 4);
                pl[i][s] += __shfl_xor(pl[i][s], 8);
            }
        if (r16 == 0) {
#pragma unroll
            for (int i = 0; i < 4; i++)
#pragma unroll
                for (int s = 0; s < 6; s++) red[g * 4 + i][wv][s] = pl[i][s];
        }
        __syncthreads();                          // red ready; Fl[cur] reads done

        // ---- finalize: 16 pts x 8 lanes -> log-softmax + scatter ----
        if (tid < 128) {
            const int lpt = tid >> 3, j = tid & 7;
            float v = -1e30f;
            if (j < 6) {
                v = biasj;
#pragma unroll
                for (int w = 0; w < 8; w++) v += red[lpt][w][j];
            }
            float mx = v;
            mx = fmaxf(mx, __shfl_xor(mx, 1));
            mx = fmaxf(mx, __shfl_xor(mx, 2));
            mx = fmaxf(mx, __shfl_xor(mx, 4));
            float e = (j < 6) ? expf(v - mx) : 0.f;
            float se = e;
            se += __shfl_xor(se, 1);
            se += __shfl_xor(se, 2);
            se += __shfl_xor(se, 4);
            float lse = mx + logf(se);
            const int gpt = ck * 16 + lpt;
            if (gpt < npts) {
                if (j < 6) red[lpt][0][j] = v - lse;   // intra-wave LDS, ordered
                const int pid = plds[gpt];
                float* orow = out + (size_t)pid * OUTK;
                for (int k = j; k < OUTK; k += 8) {
                    int jj = k - shc;
                    orow[k] = (jj >= 0 && jj < lnc) ? red[lpt][0][jj] : 0.f;
                }
            }
        }
    }
}

extern "C" void kernel_launch(void* const* d_in, const int* in_sizes, int n_in,
                              void* d_out, int out_size, void* d_ws, size_t ws_size,
                              hipStream_t stream) {
    const float* F      = (const float*)d_in[0];
    const float* W1     = (const float*)d_in[1];
    const float* gamma  = (const float*)d_in[2];
    const float* beta   = (const float*)d_in[3];
    const float* Wc     = (const float*)d_in[4];
    const float* bias   = (const float*)d_in[5];
    const int*  cats    = (const int*)d_in[6];
    const int*  shifts  = (const int*)d_in[7];
    const int*  seglens = (const int*)d_in[8];
    float* out = (float*)d_out;
    float* ws  = (float*)d_ws;
    u16* Fb  = (u16*)(ws + OFF_FB);
    u16* FbT = (u16*)(ws + OFF_FBT);
    u16* W1T = (u16*)(ws + OFF_W1T);

    int nchunk = 64;
    if (ws_size < ((size_t)OFF_GP + 40960ull * 64) * 4) nchunk = 32;
    if (ws_size < ((size_t)OFF_GP + 40960ull * 32) * 4) nchunk = 16;
    const int Kc = N_PTS / nchunk;

    hipLaunchKernelGGL(k0_cvt,      dim3(2048), dim3(256), 0, stream, F, Fb, FbT);
    hipLaunchKernelGGL(k0b_w1t,     dim3(256),  dim3(256), 0, stream, W1, W1T);
    hipLaunchKernelGGL(k1_gram,     dim3(10 * nchunk), dim3(256), 0, stream, FbT, ws, nchunk, Kc);
    hipLaunchKernelGGL(k1b_colsum,  dim3(256),  dim3(256), 0, stream, FbT, ws);
    hipLaunchKernelGGL(k2a_reduce,  dim3(160),  dim3(256), 0, stream, ws, nchunk);
    hipLaunchKernelGGL(k2b_stats,   dim3(128),  dim3(256), 0, stream, W1, gamma, beta, ws);
    hipLaunchKernelGGL(k3_hist,     dim3(64),   dim3(256), 0, stream, cats, ws);
    hipLaunchKernelGGL(k4_prefix,   dim3(1),    dim3(64),  0, stream, ws);
    hipLaunchKernelGGL(k4b_scatter, dim3(64),   dim3(256), 0, stream, cats, ws);
    hipLaunchKernelGGL(k5_mfma,     dim3(272),  dim3(512), 0, stream,
                       Fb, W1T, Wc, bias, shifts, seglens, ws, out);
}

// Round 9
// 166.277 us; speedup vs baseline: 1.1274x; 1.1274x over previous
//
#include <hip/hip_runtime.h>
#include <hip/hip_bf16.h>
#include <math.h>

#define N_PTS 32768
#define IN_F  256
#define NUM_CAT 16
#define CF    4096
#define NSEG  6
#define OUTK  50
#define BN_EPS 1e-5f

typedef unsigned short u16;
typedef __attribute__((ext_vector_type(8))) short bf16x8;
typedef __attribute__((ext_vector_type(4))) float f32x4;
typedef __attribute__((ext_vector_type(8))) unsigned short u16x8;

// ---- ws layout (float offsets) ----
#define OFF_G     0u          // 256*256
#define OFF_FBAR  65536u      // 256
#define OFF_SCALE 65792u      // 4096
#define OFF_SHIFT 69888u      // 4096
#define OFF_INT   73984u      // int region (33440 ints)
#define OFF_FB    107424u     // F bf16 [32768][256]
#define OFF_FBT   4301728u    // F^T bf16 [256][32768]
#define OFF_W1T   8496032u    // W1T bf16 [16][256 n][256 k]
#define OFF_GP    9020320u    // Gram partials [chunk][40960]
#define IO_COUNTS 0
#define IO_CATOFF 16
#define IO_TILEST 33
#define IO_NTILES 50
#define IO_CURSOR 51
#define IO_ORDER  67
#define IO_TILECAT 32835      // packed: c | (npts-1)<<4 | base<<10   (64-pt tiles)

__device__ __forceinline__ void gload_lds16(const void* g, void* l) {
    __builtin_amdgcn_global_load_lds(
        (const __attribute__((address_space(1))) void*)g,
        (__attribute__((address_space(3))) void*)l,
        16, 0, 0);
}
__device__ __forceinline__ u16 f2bf(float f) {
    unsigned int u = __float_as_uint(f);
    return (u16)((u + 0x7FFF + ((u >> 16) & 1)) >> 16);
}
__device__ __forceinline__ float bf2f(u16 h) {
    return __uint_as_float((unsigned int)h << 16);
}

// ============ K0: F -> Fb (row-major bf16) AND FbT (transposed bf16) ============
__global__ __launch_bounds__(256) void k0_cvt(const float* __restrict__ F,
                                              u16* __restrict__ Fb,
                                              u16* __restrict__ FbT) {
    const int pb = blockIdx.x >> 2, fb = blockIdx.x & 3;
    const int p0 = pb * 64, f0 = fb * 64;
    const int tid = threadIdx.x;
    __shared__ u16 T[64][72];
    {
        int p = tid >> 2, fq = tid & 3;
        const float* src = &F[(size_t)(p0 + p) * IN_F + f0 + fq * 16];
        u16x8 o0, o1;
        float4 v0 = *(const float4*)&src[0];
        float4 v1 = *(const float4*)&src[4];
        float4 v2 = *(const float4*)&src[8];
        float4 v3 = *(const float4*)&src[12];
        o0[0]=f2bf(v0.x); o0[1]=f2bf(v0.y); o0[2]=f2bf(v0.z); o0[3]=f2bf(v0.w);
        o0[4]=f2bf(v1.x); o0[5]=f2bf(v1.y); o0[6]=f2bf(v1.z); o0[7]=f2bf(v1.w);
        o1[0]=f2bf(v2.x); o1[1]=f2bf(v2.y); o1[2]=f2bf(v2.z); o1[3]=f2bf(v2.w);
        o1[4]=f2bf(v3.x); o1[5]=f2bf(v3.y); o1[6]=f2bf(v3.z); o1[7]=f2bf(v3.w);
        u16* dst = &Fb[(size_t)(p0 + p) * IN_F + f0 + fq * 16];
        *(u16x8*)dst = o0; *(u16x8*)&dst[8] = o1;
        *(u16x8*)&T[p][fq * 16] = o0; *(u16x8*)&T[p][fq * 16 + 8] = o1;
    }
    __syncthreads();
    {
        int f = tid >> 2, pq = tid & 3;
        u16x8 a0, a1;
#pragma unroll
        for (int m = 0; m < 8; m++) { a0[m] = T[pq*16 + m][f]; a1[m] = T[pq*16 + 8 + m][f]; }
        u16* dst = &FbT[(size_t)(f0 + f) * N_PTS + p0 + pq * 16];
        *(u16x8*)dst = a0; *(u16x8*)&dst[8] = a1;
    }
}

// ============ K0b: W1 [256][4096] -> W1T bf16 [c][n][k] ============
__global__ __launch_bounds__(256) void k0b_w1t(const float* __restrict__ W1,
                                               u16* __restrict__ W1T) {
    __shared__ u16 T[64][65];
    const int kb = blockIdx.x & 3, jb = blockIdx.x >> 2;
    const int tid = threadIdx.x;
    {
        int kk = tid >> 2, j4 = (tid & 3) * 16;
        const float* src = &W1[(size_t)(kb * 64 + kk) * CF + jb * 64 + j4];
#pragma unroll
        for (int q = 0; q < 4; q++) {
            float4 v = *(const float4*)&src[q * 4];
            T[kk][j4 + q * 4 + 0] = f2bf(v.x); T[kk][j4 + q * 4 + 1] = f2bf(v.y);
            T[kk][j4 + q * 4 + 2] = f2bf(v.z); T[kk][j4 + q * 4 + 3] = f2bf(v.w);
        }
    }
    __syncthreads();
    {
        int jj = tid >> 2, ks = (tid & 3) * 16;
        int c = jb >> 2, n = (jb & 3) * 64 + jj;
        u16* dst = &W1T[((size_t)(c * 256 + n)) * 256 + kb * 64 + ks];
        u16x8 o0, o1;
#pragma unroll
        for (int m = 0; m < 8; m++) { o0[m] = T[ks + m][jj]; o1[m] = T[ks + 8 + m][jj]; }
        *(u16x8*)dst = o0;
        *(u16x8*)&dst[8] = o1;
    }
}

// ============ K1: Gram via bf16 MFMA (10 symmetric tiles x nchunk K-chunks) ============
__global__ __launch_bounds__(256) void k1_gram(const u16* __restrict__ FbT,
                                               float* __restrict__ ws,
                                               int nchunk, int Kc) {
    const int TI[10] = {0,0,0,0,1,1,1,2,2,3};
    const int TJ[10] = {0,1,2,3,1,2,3,2,3,3};
    const int t = blockIdx.x % 10, chunk = blockIdx.x / 10;
    const int i0 = TI[t] * 64, j0 = TJ[t] * 64;
    const int r0 = chunk * Kc;
    const int tid = threadIdx.x;
    const int wv = tid >> 6, ln = tid & 63, g = ln >> 4, r16 = ln & 15;
    __shared__ __align__(16) u16 SA[2][4096];
    __shared__ __align__(16) u16 SB[2][4096];

    const int q0 = wv * 2, q1 = wv * 2 + 1;
    const int u_a = ((q0 * 64 + ln) & 7), row_a = (q0 * 64 + ln) >> 3;
    const int u_b = ((q1 * 64 + ln) & 7), row_b = (q1 * 64 + ln) >> 3;
    const int ka = ((u_a ^ (row_a & 7)) << 3), kb2 = ((u_b ^ (row_b & 7)) << 3);

    f32x4 acc[4];
#pragma unroll
    for (int nt = 0; nt < 4; nt++)
#pragma unroll
        for (int i = 0; i < 4; i++) acc[nt][i] = 0.f;

    const int nslab = Kc >> 6;
#define K1_STAGE(s, b)                                                              \
    {   int p0s = r0 + (s) * 64;                                                    \
        gload_lds16(FbT + (size_t)(i0 + row_a) * N_PTS + p0s + ka,                  \
                    (char*)SA[b] + q0 * 1024);                                      \
        gload_lds16(FbT + (size_t)(i0 + row_b) * N_PTS + p0s + kb2,                 \
                    (char*)SA[b] + q1 * 1024);                                      \
        gload_lds16(FbT + (size_t)(j0 + row_a) * N_PTS + p0s + ka,                  \
                    (char*)SB[b] + q0 * 1024);                                      \
        gload_lds16(FbT + (size_t)(j0 + row_b) * N_PTS + p0s + kb2,                 \
                    (char*)SB[b] + q1 * 1024);                                      \
    }

    K1_STAGE(0, 0);
    __syncthreads();
    for (int s = 0; s < nslab; s++) {
        const int b = s & 1;
        if (s + 1 < nslab) K1_STAGE(s + 1, b ^ 1);
#pragma unroll
        for (int ks = 0; ks < 2; ks++) {
            int ph = (ks * 4 + g) ^ (r16 & 7);
            bf16x8 a = *(const bf16x8*)((const char*)SA[b] + (wv * 16 + r16) * 128 + ph * 16);
#pragma unroll
            for (int nt = 0; nt < 4; nt++) {
                int nB = nt * 16 + r16;
                bf16x8 bb = *(const bf16x8*)((const char*)SB[b] + nB * 128 + ph * 16);
                acc[nt] = __builtin_amdgcn_mfma_f32_16x16x32_bf16(a, bb, acc[nt], 0, 0, 0);
            }
        }
        __syncthreads();
    }
    float* Gp = ws + OFF_GP + (size_t)chunk * 40960 + t * 4096;
#pragma unroll
    for (int nt = 0; nt < 4; nt++)
#pragma unroll
        for (int i = 0; i < 4; i++) {
            int row = wv * 16 + g * 4 + i, col = nt * 16 + r16;
            Gp[row * 64 + col] = acc[nt][i];
        }
}

// ============ K1b: column means from FbT; zero category counts ============
__global__ __launch_bounds__(256) void k1b_colsum(const u16* __restrict__ FbT,
                                                  float* __restrict__ ws) {
    const int row = blockIdx.x, tid = threadIdx.x;
    const u16* r = FbT + (size_t)row * N_PTS;
    float s = 0.f;
    for (int i = tid * 8; i < N_PTS; i += 2048) {
        u16x8 v = *(const u16x8*)&r[i];
#pragma unroll
        for (int m = 0; m < 8; m++) s += bf2f(v[m]);
    }
#pragma unroll
    for (int off = 32; off >= 1; off >>= 1) s += __shfl_xor(s, off);
    __shared__ float ps[4];
    if ((tid & 63) == 0) ps[tid >> 6] = s;
    __syncthreads();
    if (tid == 0) ws[OFF_FBAR + row] = (ps[0] + ps[1] + ps[2] + ps[3]) * (1.0f / N_PTS);
    if (blockIdx.x == 0 && tid < 16) ((int*)(ws + OFF_INT))[IO_COUNTS + tid] = 0;
}

// ============ K2a: coalesced reduce of Gram partials -> symmetric G ============
__global__ __launch_bounds__(256) void k2a_reduce(float* __restrict__ ws, int nchunk) {
    const int TI[10] = {0,0,0,0,1,1,1,2,2,3};
    const int TJ[10] = {0,1,2,3,1,2,3,2,3,3};
    const int e = blockIdx.x * 256 + threadIdx.x;   // 0..40959
    const float* p = ws + OFF_GP + e;
    float s = 0.f;
#pragma unroll 8
    for (int c = 0; c < nchunk; c++) s += p[(size_t)c * 40960];
    int t = e >> 12, x = (e >> 6) & 63, y = e & 63;
    int a = TI[t] * 64 + x, b = TJ[t] * 64 + y;
    ws[OFF_G + a * 256 + b] = s;
    ws[OFF_G + b * 256 + a] = s;
}

// ============ K2b: per-column mu/var -> scale/shift (32 cols/block) ============
__global__ __launch_bounds__(256) void k2b_stats(const float* __restrict__ W1,
                                                 const float* __restrict__ gamma,
                                                 const float* __restrict__ beta,
                                                 float* __restrict__ ws) {
    const int tid = threadIdx.x;
    const int j0 = blockIdx.x * 32;
    __shared__ __align__(16) float wl[32][256];
    __shared__ float pw[32][8];
#pragma unroll
    for (int q = 0; q < 8; q++) {
        float4 v = *(const float4*)&W1[(size_t)tid * CF + j0 + q * 4];
        wl[q * 4 + 0][tid] = v.x; wl[q * 4 + 1][tid] = v.y;
        wl[q * 4 + 2][tid] = v.z; wl[q * 4 + 3][tid] = v.w;
    }
    __syncthreads();
    float acc[32];
#pragma unroll
    for (int jj = 0; jj < 32; jj++) acc[jj] = 0.f;
    const float* G = ws + OFF_G;
    for (int b = 0; b < 256; b++) {
        float g = G[b * 256 + tid];
#pragma unroll
        for (int jj = 0; jj < 32; jj++) acc[jj] += g * wl[jj][b];
    }
    float fb = ws[OFF_FBAR + tid];
    const int lane = tid & 63, wave = tid >> 6;
#pragma unroll
    for (int jj = 0; jj < 32; jj++) {
        float v = wl[jj][tid] * acc[jj];
        float m = fb * wl[jj][tid];
#pragma unroll
        for (int off = 32; off >= 1; off >>= 1) {
            v += __shfl_xor(v, off);
            m += __shfl_xor(m, off);
        }
        if (lane == 0) { pw[jj][wave * 2] = v; pw[jj][wave * 2 + 1] = m; }
    }
    __syncthreads();
    if (tid < 32) {
        int jj = tid;
        float v = 0.f, m = 0.f;
        for (int w2 = 0; w2 < 4; w2++) { v += pw[jj][w2 * 2]; m += pw[jj][w2 * 2 + 1]; }
        float mu  = m;
        float var = v * (1.0f / N_PTS) - mu * mu;
        float sc  = gamma[j0 + jj] * rsqrtf(var + BN_EPS);
        float sh  = beta[j0 + jj] - mu * sc;
        ws[OFF_SCALE + j0 + jj] = sc;
        ws[OFF_SHIFT + j0 + jj] = sh;
    }
}

// ============ K3: category histogram ============
__global__ __launch_bounds__(256) void k3_hist(const int* __restrict__ cats,
                                               float* __restrict__ ws) {
    __shared__ int h[16];
    int tid = threadIdx.x;
    if (tid < 16) h[tid] = 0;
    __syncthreads();
    for (int n = blockIdx.x * 256 + tid; n < N_PTS; n += 64 * 256)
        atomicAdd(&h[cats[n]], 1);
    __syncthreads();
    int* wi = (int*)(ws + OFF_INT);
    if (tid < 16) atomicAdd(&wi[IO_COUNTS + tid], h[tid]);
}

// ============ K4: prefix sums + packed per-tile LUT (64-pt tiles) ============
__global__ void k4_prefix(float* __restrict__ ws) {
    int* wi = (int*)(ws + OFF_INT);
    if (threadIdx.x == 0) {
        int co = 0, ts = 0;
        wi[IO_CATOFF] = 0; wi[IO_TILEST] = 0;
        for (int c = 0; c < 16; c++) {
            int cnt = wi[IO_COUNTS + c];
            wi[IO_CURSOR + c] = co;
            int nt = (cnt + 63) >> 6;
            for (int lt = 0; lt < nt; lt++) {
                int npts = min(64, cnt - lt * 64);
                int b = co + lt * 64;
                wi[IO_TILECAT + ts + lt] = c | ((npts - 1) << 4) | (b << 10);
            }
            co += cnt; ts += nt;
            wi[IO_CATOFF + c + 1] = co;
            wi[IO_TILEST + c + 1] = ts;
        }
        wi[IO_NTILES] = ts;
    }
}

// ============ K4b: grouped scatter, two-level (block reservation + LDS ranks) ====
__global__ __launch_bounds__(256) void k4b_scatter(const int* __restrict__ cats,
                                                   float* __restrict__ ws) {
    int* wi = (int*)(ws + OFF_INT);
    __shared__ int lh[16], lbase[16];
    const int tid = threadIdx.x;
    const int n0 = blockIdx.x * 512;
    if (tid < 16) lh[tid] = 0;
    __syncthreads();
    const int cA = cats[n0 + tid];
    const int cB = cats[n0 + 256 + tid];
    atomicAdd(&lh[cA], 1);
    atomicAdd(&lh[cB], 1);
    __syncthreads();
    if (tid < 16) lbase[tid] = atomicAdd(&wi[IO_CURSOR + tid], lh[tid]);
    __syncthreads();
    if (tid < 16) lh[tid] = 0;
    __syncthreads();
    int rA = atomicAdd(&lh[cA], 1);
    wi[IO_ORDER + lbase[cA] + rA] = n0 + tid;
    int rB = atomicAdd(&lh[cB], 1);
    wi[IO_ORDER + lbase[cB] + rB] = n0 + 256 + tid;
}

// ============ K5: bf16-MFMA GEMM — max occupancy, zero K-loop barriers ============
// 64 pts x 256 cols per block, 512 thr / 8 waves, wave wv owns cols wv*32..+31.
// F tile 32KB in LDS (swizzled, staged once). W fragments read DIRECTLY from
// L2-hot W1T via 2-deep register pipeline (statically indexed, full unroll).
// acc[4][2] = 32 VGPR. Finalize ONCE per block via shfl-broadcast softmax.
__global__ __launch_bounds__(512, 6) void k5_mfma(const u16* __restrict__ Fb,
                                                  const u16* __restrict__ W1T,
                                                  const float* __restrict__ Wc,
                                                  const float* __restrict__ bias,
                                                  const int* __restrict__ shifts,
                                                  const int* __restrict__ seg_lens,
                                                  const float* __restrict__ ws,
                                                  float* __restrict__ out) {
    const int* wi = (const int*)(ws + OFF_INT);
    const int t = blockIdx.x;
    if (t >= wi[IO_NTILES]) return;
    const unsigned info = (unsigned)wi[IO_TILECAT + t];
    const int c    = info & 15;
    const int npts = ((info >> 4) & 63) + 1;
    const int base = info >> 10;
    const int tid = threadIdx.x;
    const int wv = tid >> 6, ln = tid & 63;
    const int g = ln >> 4, r16 = ln & 15, r7 = r16 & 7;

    __shared__ __align__(16) u16 Fl[16384];     // 32 KB, [64 pt][32 units], ^(pt&7)
    __shared__ float red[64][8][8];             // 16 KB
    __shared__ int plds[64];

    if (tid < 64) plds[tid] = wi[IO_ORDER + base + min(tid, npts - 1)];
    // per-thread BN constants (global loads, overlap with barrier)
    const int col0 = wv * 32 + r16, col1 = col0 + 16;
    const float sc0 = ws[OFF_SCALE + c * 256 + col0];
    const float sc1 = ws[OFF_SCALE + c * 256 + col1];
    const float sh0 = ws[OFF_SHIFT + c * 256 + col0];
    const float sh1 = ws[OFF_SHIFT + c * 256 + col1];
    const float biasj = ((tid & 7) < 6) ? bias[tid & 7] : 0.f;
    const int shc = shifts[c], lnc = seg_lens[c];
    __syncthreads();                            // plds visible

    // ---- stage F tile: 2048 16B units, 4 gload_lds per wave ----
#pragma unroll
    for (int s = 0; s < 4; s++) {
        int flat = (wv * 4 + s) * 64 + ln;
        int pt = flat >> 5, u = flat & 31;
        const u16* src = Fb + (size_t)plds[pt] * 256 + ((u ^ (pt & 7)) << 3);
        gload_lds16(src, (char*)Fl + (size_t)(wv * 4 + s) * 1024);
    }

    const u16* W1Tc = W1T + (size_t)c * 65536;
    const u16* wp0 = W1Tc + (size_t)col0 * 256 + g * 8;
    const u16* wp1 = W1Tc + (size_t)col1 * 256 + g * 8;

    __syncthreads();                            // F resident (vmcnt drained)

    f32x4 acc[4][2];
#pragma unroll
    for (int mt = 0; mt < 4; mt++)
#pragma unroll
        for (int nt = 0; nt < 2; nt++)
#pragma unroll
            for (int i = 0; i < 4; i++) acc[mt][nt][i] = 0.f;

    bf16x8 bf0[2], bf1[2];
    bf0[0] = *(const bf16x8*)(wp0);
    bf1[0] = *(const bf16x8*)(wp1);

#pragma unroll
    for (int kc = 0; kc < 8; kc++) {
        if (kc < 7) {                           // 2-deep W pipeline (static idx)
            bf0[(kc + 1) & 1] = *(const bf16x8*)(wp0 + (kc + 1) * 32);
            bf1[(kc + 1) & 1] = *(const bf16x8*)(wp1 + (kc + 1) * 32);
        }
#pragma unroll
        for (int mt = 0; mt < 4; mt++) {
            int row = mt * 16 + r16;
            int ph = ((kc * 4 + g) ^ r7) * 16;
            bf16x8 af = *(const bf16x8*)((const char*)Fl + (size_t)row * 512 + ph);
            acc[mt][0] = __builtin_amdgcn_mfma_f32_16x16x32_bf16(af, bf0[kc & 1], acc[mt][0], 0, 0, 0);
            acc[mt][1] = __builtin_amdgcn_mfma_f32_16x16x32_bf16(af, bf1[kc & 1], acc[mt][1], 0, 0, 0);
        }
    }
    __builtin_amdgcn_sched_barrier(0);          // keep Wc loads out of K-loop

    // ---- epilogue (once): BN + LeakyReLU + Wc partials + 16-lane reduce ----
    float wc0[6], wc1[6];
#pragma unroll
    for (int s = 0; s < 6; s++) {
        wc0[s] = Wc[(size_t)c * 1536 + col0 * 6 + s];
        wc1[s] = Wc[(size_t)c * 1536 + col1 * 6 + s];
    }
#pragma unroll
    for (int mt = 0; mt < 4; mt++)
#pragma unroll
        for (int i = 0; i < 4; i++) {
            float x0 = acc[mt][0][i] * sc0 + sh0;  x0 = (x0 >= 0.f) ? x0 : 0.2f * x0;
            float x1 = acc[mt][1][i] * sc1 + sh1;  x1 = (x1 >= 0.f) ? x1 : 0.2f * x1;
            float pl[6];
#pragma unroll
            for (int s = 0; s < 6; s++) pl[s] = x0 * wc0[s] + x1 * wc1[s];
#pragma unroll
            for (int s = 0; s < 6; s++) {
                pl[s] += __shfl_xor(pl[s], 1);
                pl[s] += __shfl_xor(pl[s], 2);
                pl[s] += __shfl_xor(pl[s], 4);
                pl[s] += __shfl_xor(pl[s], 8);
            }
            if (r16 == 0) {
                int row = mt * 16 + g * 4 + i;
#pragma unroll
                for (int s = 0; s < 6; s++) red[row][wv][s] = pl[s];
            }
        }
    __syncthreads();

    // ---- finalize: all 512 threads = 64 pts x 8 lanes ----
    {
        const int lpt = tid >> 3, j = tid & 7;
        float v = -1e30f;
        if (j < 6) {
            v = biasj;
#pragma unroll
            for (int w = 0; w < 8; w++) v += red[lpt][w][j];
        }
        float mx = v;
        mx = fmaxf(mx, __shfl_xor(mx, 1));
        mx = fmaxf(mx, __shfl_xor(mx, 2));
        mx = fmaxf(mx, __shfl_xor(mx, 4));
        float e = (j < 6) ? expf(v - mx) : 0.f;
        float se = e;
        se += __shfl_xor(se, 1);
        se += __shfl_xor(se, 2);
        se += __shfl_xor(se, 4);
        float lsm = v - (mx + logf(se));        // valid on j<6 lanes
        if (lpt < npts) {
            const int pid = plds[lpt];
            float* orow = out + (size_t)pid * OUTK;
            const int gb = ln & 56;             // 8-lane group base within wave
#pragma unroll
            for (int it = 0; it < 7; it++) {
                int k = j + it * 8;
                int jj = k - shc;
                int jc = min(max(jj, 0), 5);
                float val = __shfl(lsm, gb | jc);
                if (k < OUTK)
                    orow[k] = (jj >= 0 && jj < lnc) ? val : 0.f;
            }
        }
    }
}

extern "C" void kernel_launch(void* const* d_in, const int* in_sizes, int n_in,
                              void* d_out, int out_size, void* d_ws, size_t ws_size,
                              hipStream_t stream) {
    const float* F      = (const float*)d_in[0];
    const float* W1     = (const float*)d_in[1];
    const float* gamma  = (const float*)d_in[2];
    const float* beta   = (const float*)d_in[3];
    const float* Wc     = (const float*)d_in[4];
    const float* bias   = (const float*)d_in[5];
    const int*  cats    = (const int*)d_in[6];
    const int*  shifts  = (const int*)d_in[7];
    const int*  seglens = (const int*)d_in[8];
    float* out = (float*)d_out;
    float* ws  = (float*)d_ws;
    u16* Fb  = (u16*)(ws + OFF_FB);
    u16* FbT = (u16*)(ws + OFF_FBT);
    u16* W1T = (u16*)(ws + OFF_W1T);

    int nchunk = 64;
    if (ws_size < ((size_t)OFF_GP + 40960ull * 64) * 4) nchunk = 32;
    if (ws_size < ((size_t)OFF_GP + 40960ull * 32) * 4) nchunk = 16;
    const int Kc = N_PTS / nchunk;

    hipLaunchKernelGGL(k0_cvt,      dim3(2048), dim3(256), 0, stream, F, Fb, FbT);
    hipLaunchKernelGGL(k0b_w1t,     dim3(256),  dim3(256), 0, stream, W1, W1T);
    hipLaunchKernelGGL(k1_gram,     dim3(10 * nchunk), dim3(256), 0, stream, FbT, ws, nchunk, Kc);
    hipLaunchKernelGGL(k1b_colsum,  dim3(256),  dim3(256), 0, stream, FbT, ws);
    hipLaunchKernelGGL(k2a_reduce,  dim3(160),  dim3(256), 0, stream, ws, nchunk);
    hipLaunchKernelGGL(k2b_stats,   dim3(128),  dim3(256), 0, stream, W1, gamma, beta, ws);
    hipLaunchKernelGGL(k3_hist,     dim3(64),   dim3(256), 0, stream, cats, ws);
    hipLaunchKernelGGL(k4_prefix,   dim3(1),    dim3(64),  0, stream, ws);
    hipLaunchKernelGGL(k4b_scatter, dim3(64),   dim3(256), 0, stream, cats, ws);
    hipLaunchKernelGGL(k5_mfma,     dim3(528),  dim3(512), 0, stream,
                       Fb, W1T, Wc, bias, shifts, seglens, ws, out);
}

// Round 10
// 165.701 us; speedup vs baseline: 1.1314x; 1.0035x over previous
//
#include <hip/hip_runtime.h>
#include <hip/hip_bf16.h>
#include <math.h>

#define N_PTS 32768
#define IN_F  256
#define NUM_CAT 16
#define CF    4096
#define NSEG  6
#define OUTK  50
#define BN_EPS 1e-5f

typedef unsigned short u16;
typedef __attribute__((ext_vector_type(8))) short bf16x8;
typedef __attribute__((ext_vector_type(4))) float f32x4;
typedef __attribute__((ext_vector_type(8))) unsigned short u16x8;

// ---- ws layout (float offsets) ----
#define OFF_G     0u          // 256*256
#define OFF_FBAR  65536u      // 256
#define OFF_SCALE 65792u      // 4096
#define OFF_SHIFT 69888u      // 4096
#define OFF_INT   73984u      // int region (33440 ints)
#define OFF_FB    107424u     // F bf16 [32768][256]
#define OFF_FBT   4301728u    // F^T bf16 [256][32768]
#define OFF_W1T   8496032u    // W1T bf16 [16][256 n][256 k]
#define OFF_GP    9020320u    // Gram partials [chunk][40960]
// k2b partials overlay the (dead-after-k2a) GP region:
#define OFF_VP    OFF_GP              // 8 * 4096 floats
#define OFF_MU    (OFF_GP + 32768u)   // 4096 floats
#define IO_COUNTS 0
#define IO_CATOFF 16
#define IO_TILEST 33
#define IO_NTILES 50
#define IO_CURSOR 51
#define IO_ORDER  67
#define IO_TILECAT 32835      // packed: c | (npts-1)<<4 | base<<10   (64-pt tiles)

__device__ __forceinline__ void gload_lds16(const void* g, void* l) {
    __builtin_amdgcn_global_load_lds(
        (const __attribute__((address_space(1))) void*)g,
        (__attribute__((address_space(3))) void*)l,
        16, 0, 0);
}
__device__ __forceinline__ u16 f2bf(float f) {
    unsigned int u = __float_as_uint(f);
    return (u16)((u + 0x7FFF + ((u >> 16) & 1)) >> 16);
}
__device__ __forceinline__ float bf2f(u16 h) {
    return __uint_as_float((unsigned int)h << 16);
}

// ============ K0: F -> Fb (row-major bf16) AND FbT (transposed bf16) ============
__global__ __launch_bounds__(256) void k0_cvt(const float* __restrict__ F,
                                              u16* __restrict__ Fb,
                                              u16* __restrict__ FbT) {
    const int pb = blockIdx.x >> 2, fb = blockIdx.x & 3;
    const int p0 = pb * 64, f0 = fb * 64;
    const int tid = threadIdx.x;
    __shared__ u16 T[64][72];
    {
        int p = tid >> 2, fq = tid & 3;
        const float* src = &F[(size_t)(p0 + p) * IN_F + f0 + fq * 16];
        u16x8 o0, o1;
        float4 v0 = *(const float4*)&src[0];
        float4 v1 = *(const float4*)&src[4];
        float4 v2 = *(const float4*)&src[8];
        float4 v3 = *(const float4*)&src[12];
        o0[0]=f2bf(v0.x); o0[1]=f2bf(v0.y); o0[2]=f2bf(v0.z); o0[3]=f2bf(v0.w);
        o0[4]=f2bf(v1.x); o0[5]=f2bf(v1.y); o0[6]=f2bf(v1.z); o0[7]=f2bf(v1.w);
        o1[0]=f2bf(v2.x); o1[1]=f2bf(v2.y); o1[2]=f2bf(v2.z); o1[3]=f2bf(v2.w);
        o1[4]=f2bf(v3.x); o1[5]=f2bf(v3.y); o1[6]=f2bf(v3.z); o1[7]=f2bf(v3.w);
        u16* dst = &Fb[(size_t)(p0 + p) * IN_F + f0 + fq * 16];
        *(u16x8*)dst = o0; *(u16x8*)&dst[8] = o1;
        *(u16x8*)&T[p][fq * 16] = o0; *(u16x8*)&T[p][fq * 16 + 8] = o1;
    }
    __syncthreads();
    {
        int f = tid >> 2, pq = tid & 3;
        u16x8 a0, a1;
#pragma unroll
        for (int m = 0; m < 8; m++) { a0[m] = T[pq*16 + m][f]; a1[m] = T[pq*16 + 8 + m][f]; }
        u16* dst = &FbT[(size_t)(f0 + f) * N_PTS + p0 + pq * 16];
        *(u16x8*)dst = a0; *(u16x8*)&dst[8] = a1;
    }
}

// ============ K0b: W1 [256][4096] -> W1T bf16 [c][n][k] ============
__global__ __launch_bounds__(256) void k0b_w1t(const float* __restrict__ W1,
                                               u16* __restrict__ W1T) {
    __shared__ u16 T[64][65];
    const int kb = blockIdx.x & 3, jb = blockIdx.x >> 2;
    const int tid = threadIdx.x;
    {
        int kk = tid >> 2, j4 = (tid & 3) * 16;
        const float* src = &W1[(size_t)(kb * 64 + kk) * CF + jb * 64 + j4];
#pragma unroll
        for (int q = 0; q < 4; q++) {
            float4 v = *(const float4*)&src[q * 4];
            T[kk][j4 + q * 4 + 0] = f2bf(v.x); T[kk][j4 + q * 4 + 1] = f2bf(v.y);
            T[kk][j4 + q * 4 + 2] = f2bf(v.z); T[kk][j4 + q * 4 + 3] = f2bf(v.w);
        }
    }
    __syncthreads();
    {
        int jj = tid >> 2, ks = (tid & 3) * 16;
        int c = jb >> 2, n = (jb & 3) * 64 + jj;
        u16* dst = &W1T[((size_t)(c * 256 + n)) * 256 + kb * 64 + ks];
        u16x8 o0, o1;
#pragma unroll
        for (int m = 0; m < 8; m++) { o0[m] = T[ks + m][jj]; o1[m] = T[ks + 8 + m][jj]; }
        *(u16x8*)dst = o0;
        *(u16x8*)&dst[8] = o1;
    }
}

// ============ K1: Gram via bf16 MFMA (10 symmetric tiles x nchunk K-chunks) ============
__global__ __launch_bounds__(256) void k1_gram(const u16* __restrict__ FbT,
                                               float* __restrict__ ws,
                                               int nchunk, int Kc) {
    const int TI[10] = {0,0,0,0,1,1,1,2,2,3};
    const int TJ[10] = {0,1,2,3,1,2,3,2,3,3};
    const int t = blockIdx.x % 10, chunk = blockIdx.x / 10;
    const int i0 = TI[t] * 64, j0 = TJ[t] * 64;
    const int r0 = chunk * Kc;
    const int tid = threadIdx.x;
    const int wv = tid >> 6, ln = tid & 63, g = ln >> 4, r16 = ln & 15;
    __shared__ __align__(16) u16 SA[2][4096];
    __shared__ __align__(16) u16 SB[2][4096];

    const int q0 = wv * 2, q1 = wv * 2 + 1;
    const int u_a = ((q0 * 64 + ln) & 7), row_a = (q0 * 64 + ln) >> 3;
    const int u_b = ((q1 * 64 + ln) & 7), row_b = (q1 * 64 + ln) >> 3;
    const int ka = ((u_a ^ (row_a & 7)) << 3), kb2 = ((u_b ^ (row_b & 7)) << 3);

    f32x4 acc[4];
#pragma unroll
    for (int nt = 0; nt < 4; nt++)
#pragma unroll
        for (int i = 0; i < 4; i++) acc[nt][i] = 0.f;

    const int nslab = Kc >> 6;
#define K1_STAGE(s, b)                                                              \
    {   int p0s = r0 + (s) * 64;                                                    \
        gload_lds16(FbT + (size_t)(i0 + row_a) * N_PTS + p0s + ka,                  \
                    (char*)SA[b] + q0 * 1024);                                      \
        gload_lds16(FbT + (size_t)(i0 + row_b) * N_PTS + p0s + kb2,                 \
                    (char*)SA[b] + q1 * 1024);                                      \
        gload_lds16(FbT + (size_t)(j0 + row_a) * N_PTS + p0s + ka,                  \
                    (char*)SB[b] + q0 * 1024);                                      \
        gload_lds16(FbT + (size_t)(j0 + row_b) * N_PTS + p0s + kb2,                 \
                    (char*)SB[b] + q1 * 1024);                                      \
    }

    K1_STAGE(0, 0);
    __syncthreads();
    for (int s = 0; s < nslab; s++) {
        const int b = s & 1;
        if (s + 1 < nslab) K1_STAGE(s + 1, b ^ 1);
#pragma unroll
        for (int ks = 0; ks < 2; ks++) {
            int ph = (ks * 4 + g) ^ (r16 & 7);
            bf16x8 a = *(const bf16x8*)((const char*)SA[b] + (wv * 16 + r16) * 128 + ph * 16);
#pragma unroll
            for (int nt = 0; nt < 4; nt++) {
                int nB = nt * 16 + r16;
                bf16x8 bb = *(const bf16x8*)((const char*)SB[b] + nB * 128 + ph * 16);
                acc[nt] = __builtin_amdgcn_mfma_f32_16x16x32_bf16(a, bb, acc[nt], 0, 0, 0);
            }
        }
        __syncthreads();
    }
    float* Gp = ws + OFF_GP + (size_t)chunk * 40960 + t * 4096;
#pragma unroll
    for (int nt = 0; nt < 4; nt++)
#pragma unroll
        for (int i = 0; i < 4; i++) {
            int row = wv * 16 + g * 4 + i, col = nt * 16 + r16;
            Gp[row * 64 + col] = acc[nt][i];
        }
}

// ============ K1b: column means from FbT; zero category counts ============
__global__ __launch_bounds__(256) void k1b_colsum(const u16* __restrict__ FbT,
                                                  float* __restrict__ ws) {
    const int row = blockIdx.x, tid = threadIdx.x;
    const u16* r = FbT + (size_t)row * N_PTS;
    float s = 0.f;
    for (int i = tid * 8; i < N_PTS; i += 2048) {
        u16x8 v = *(const u16x8*)&r[i];
#pragma unroll
        for (int m = 0; m < 8; m++) s += bf2f(v[m]);
    }
#pragma unroll
    for (int off = 32; off >= 1; off >>= 1) s += __shfl_xor(s, off);
    __shared__ float ps[4];
    if ((tid & 63) == 0) ps[tid >> 6] = s;
    __syncthreads();
    if (tid == 0) ws[OFF_FBAR + row] = (ps[0] + ps[1] + ps[2] + ps[3]) * (1.0f / N_PTS);
    if (blockIdx.x == 0 && tid < 16) ((int*)(ws + OFF_INT))[IO_COUNTS + tid] = 0;
}

// ============ K2a: coalesced reduce of Gram partials -> symmetric G ============
__global__ __launch_bounds__(256) void k2a_reduce(float* __restrict__ ws, int nchunk) {
    const int TI[10] = {0,0,0,0,1,1,1,2,2,3};
    const int TJ[10] = {0,1,2,3,1,2,3,2,3,3};
    const int e = blockIdx.x * 256 + threadIdx.x;   // 0..40959
    const float* p = ws + OFF_GP + e;
    float s = 0.f;
#pragma unroll 8
    for (int c = 0; c < nchunk; c++) s += p[(size_t)c * 40960];
    int t = e >> 12, x = (e >> 6) & 63, y = e & 63;
    int a = TI[t] * 64 + x, b = TJ[t] * 64 + y;
    ws[OFF_G + a * 256 + b] = s;
    ws[OFF_G + b * 256 + a] = s;
}

// ============ K2b: split-b partials of w^T G w  (128 colgroups x 8 b-splits) ============
// v_j = sum_splits sum_a w_j[a] * (sum_{b in split} G[b][a] w_j[b]); exact decomposition.
__global__ __launch_bounds__(256) void k2b_stats(const float* __restrict__ W1,
                                                 float* __restrict__ ws) {
    const int tid = threadIdx.x;
    const int jg = blockIdx.x >> 3, sp = blockIdx.x & 7;
    const int j0 = jg * 32;
    __shared__ __align__(16) float wl[32][256];
    __shared__ float pwv[32][4], pwm[32][4];
#pragma unroll
    for (int q = 0; q < 8; q++) {
        float4 v = *(const float4*)&W1[(size_t)tid * CF + j0 + q * 4];
        wl[q * 4 + 0][tid] = v.x; wl[q * 4 + 1][tid] = v.y;
        wl[q * 4 + 2][tid] = v.z; wl[q * 4 + 3][tid] = v.w;
    }
    __syncthreads();
    float acc[32];
#pragma unroll
    for (int jj = 0; jj < 32; jj++) acc[jj] = 0.f;
    const float* G = ws + OFF_G + sp * 32 * 256;
#pragma unroll 4
    for (int b = 0; b < 32; b++) {
        float g = G[b * 256 + tid];
        const int gb = sp * 32 + b;
#pragma unroll
        for (int jj = 0; jj < 32; jj++) acc[jj] += g * wl[jj][gb];
    }
    const int lane = tid & 63, wave = tid >> 6;
    const float fb = ws[OFF_FBAR + tid];
#pragma unroll
    for (int jj = 0; jj < 32; jj++) {
        float v = wl[jj][tid] * acc[jj];
#pragma unroll
        for (int off = 32; off >= 1; off >>= 1) v += __shfl_xor(v, off);
        if (lane == 0) pwv[jj][wave] = v;
        if (sp == 0) {
            float m = fb * wl[jj][tid];
#pragma unroll
            for (int off = 32; off >= 1; off >>= 1) m += __shfl_xor(m, off);
            if (lane == 0) pwm[jj][wave] = m;
        }
    }
    __syncthreads();
    if (tid < 32) {
        float v = pwv[tid][0] + pwv[tid][1] + pwv[tid][2] + pwv[tid][3];
        ws[OFF_VP + sp * 4096 + j0 + tid] = v;
        if (sp == 0) {
            float m = pwm[tid][0] + pwm[tid][1] + pwm[tid][2] + pwm[tid][3];
            ws[OFF_MU + j0 + tid] = m;
        }
    }
}

// ============ K2c: combine partials -> scale/shift ============
__global__ __launch_bounds__(256) void k2c_finish(const float* __restrict__ gamma,
                                                  const float* __restrict__ beta,
                                                  float* __restrict__ ws) {
    const int j = blockIdx.x * 256 + threadIdx.x;   // 16 blocks -> 4096
    float v = 0.f;
#pragma unroll
    for (int sp = 0; sp < 8; sp++) v += ws[OFF_VP + sp * 4096 + j];
    const float mu = ws[OFF_MU + j];
    const float var = v * (1.0f / N_PTS) - mu * mu;
    const float sc = gamma[j] * rsqrtf(var + BN_EPS);
    ws[OFF_SCALE + j] = sc;
    ws[OFF_SHIFT + j] = beta[j] - mu * sc;
}

// ============ K3: category histogram ============
__global__ __launch_bounds__(256) void k3_hist(const int* __restrict__ cats,
                                               float* __restrict__ ws) {
    __shared__ int h[16];
    int tid = threadIdx.x;
    if (tid < 16) h[tid] = 0;
    __syncthreads();
    for (int n = blockIdx.x * 256 + tid; n < N_PTS; n += 64 * 256)
        atomicAdd(&h[cats[n]], 1);
    __syncthreads();
    int* wi = (int*)(ws + OFF_INT);
    if (tid < 16) atomicAdd(&wi[IO_COUNTS + tid], h[tid]);
}

// ============ K4: prefix sums + packed per-tile LUT (64-pt tiles) ============
__global__ void k4_prefix(float* __restrict__ ws) {
    int* wi = (int*)(ws + OFF_INT);
    if (threadIdx.x == 0) {
        int co = 0, ts = 0;
        wi[IO_CATOFF] = 0; wi[IO_TILEST] = 0;
        for (int c = 0; c < 16; c++) {
            int cnt = wi[IO_COUNTS + c];
            wi[IO_CURSOR + c] = co;
            int nt = (cnt + 63) >> 6;
            for (int lt = 0; lt < nt; lt++) {
                int npts = min(64, cnt - lt * 64);
                int b = co + lt * 64;
                wi[IO_TILECAT + ts + lt] = c | ((npts - 1) << 4) | (b << 10);
            }
            co += cnt; ts += nt;
            wi[IO_CATOFF + c + 1] = co;
            wi[IO_TILEST + c + 1] = ts;
        }
        wi[IO_NTILES] = ts;
    }
}

// ============ K4b: grouped scatter, two-level (block reservation + LDS ranks) ====
__global__ __launch_bounds__(256) void k4b_scatter(const int* __restrict__ cats,
                                                   float* __restrict__ ws) {
    int* wi = (int*)(ws + OFF_INT);
    __shared__ int lh[16], lbase[16];
    const int tid = threadIdx.x;
    const int n0 = blockIdx.x * 512;
    if (tid < 16) lh[tid] = 0;
    __syncthreads();
    const int cA = cats[n0 + tid];
    const int cB = cats[n0 + 256 + tid];
    atomicAdd(&lh[cA], 1);
    atomicAdd(&lh[cB], 1);
    __syncthreads();
    if (tid < 16) lbase[tid] = atomicAdd(&wi[IO_CURSOR + tid], lh[tid]);
    __syncthreads();
    if (tid < 16) lh[tid] = 0;
    __syncthreads();
    int rA = atomicAdd(&lh[cA], 1);
    wi[IO_ORDER + lbase[cA] + rA] = n0 + tid;
    int rB = atomicAdd(&lh[cB], 1);
    wi[IO_ORDER + lbase[cB] + rB] = n0 + 256 + tid;
}

// ============ K5: bf16-MFMA GEMM — max occupancy, zero K-loop barriers ============
__global__ __launch_bounds__(512, 6) void k5_mfma(const u16* __restrict__ Fb,
                                                  const u16* __restrict__ W1T,
                                                  const float* __restrict__ Wc,
                                                  const float* __restrict__ bias,
                                                  const int* __restrict__ shifts,
                                                  const int* __restrict__ seg_lens,
                                                  const float* __restrict__ ws,
                                                  float* __restrict__ out) {
    const int* wi = (const int*)(ws + OFF_INT);
    const int t = blockIdx.x;
    if (t >= wi[IO_NTILES]) return;
    const unsigned info = (unsigned)wi[IO_TILECAT + t];
    const int c    = info & 15;
    const int npts = ((info >> 4) & 63) + 1;
    const int base = info >> 10;
    const int tid = threadIdx.x;
    const int wv = tid >> 6, ln = tid & 63;
    const int g = ln >> 4, r16 = ln & 15, r7 = r16 & 7;

    __shared__ __align__(16) u16 Fl[16384];     // 32 KB, [64 pt][32 units], ^(pt&7)
    __shared__ float red[64][8][8];             // 16 KB
    __shared__ int plds[64];

    if (tid < 64) plds[tid] = wi[IO_ORDER + base + min(tid, npts - 1)];
    const int col0 = wv * 32 + r16, col1 = col0 + 16;
    const float sc0 = ws[OFF_SCALE + c * 256 + col0];
    const float sc1 = ws[OFF_SCALE + c * 256 + col1];
    const float sh0 = ws[OFF_SHIFT + c * 256 + col0];
    const float sh1 = ws[OFF_SHIFT + c * 256 + col1];
    const float biasj = ((tid & 7) < 6) ? bias[tid & 7] : 0.f;
    const int shc = shifts[c], lnc = seg_lens[c];
    __syncthreads();                            // plds visible

#pragma unroll
    for (int s = 0; s < 4; s++) {
        int flat = (wv * 4 + s) * 64 + ln;
        int pt = flat >> 5, u = flat & 31;
        const u16* src = Fb + (size_t)plds[pt] * 256 + ((u ^ (pt & 7)) << 3);
        gload_lds16(src, (char*)Fl + (size_t)(wv * 4 + s) * 1024);
    }

    const u16* W1Tc = W1T + (size_t)c * 65536;
    const u16* wp0 = W1Tc + (size_t)col0 * 256 + g * 8;
    const u16* wp1 = W1Tc + (size_t)col1 * 256 + g * 8;

    __syncthreads();                            // F resident (vmcnt drained)

    f32x4 acc[4][2];
#pragma unroll
    for (int mt = 0; mt < 4; mt++)
#pragma unroll
        for (int nt = 0; nt < 2; nt++)
#pragma unroll
            for (int i = 0; i < 4; i++) acc[mt][nt][i] = 0.f;

    bf16x8 bf0[2], bf1[2];
    bf0[0] = *(const bf16x8*)(wp0);
    bf1[0] = *(const bf16x8*)(wp1);

#pragma unroll
    for (int kc = 0; kc < 8; kc++) {
        if (kc < 7) {
            bf0[(kc + 1) & 1] = *(const bf16x8*)(wp0 + (kc + 1) * 32);
            bf1[(kc + 1) & 1] = *(const bf16x8*)(wp1 + (kc + 1) * 32);
        }
#pragma unroll
        for (int mt = 0; mt < 4; mt++) {
            int row = mt * 16 + r16;
            int ph = ((kc * 4 + g) ^ r7) * 16;
            bf16x8 af = *(const bf16x8*)((const char*)Fl + (size_t)row * 512 + ph);
            acc[mt][0] = __builtin_amdgcn_mfma_f32_16x16x32_bf16(af, bf0[kc & 1], acc[mt][0], 0, 0, 0);
            acc[mt][1] = __builtin_amdgcn_mfma_f32_16x16x32_bf16(af, bf1[kc & 1], acc[mt][1], 0, 0, 0);
        }
    }
    __builtin_amdgcn_sched_barrier(0);

    float wc0[6], wc1[6];
#pragma unroll
    for (int s = 0; s < 6; s++) {
        wc0[s] = Wc[(size_t)c * 1536 + col0 * 6 + s];
        wc1[s] = Wc[(size_t)c * 1536 + col1 * 6 + s];
    }
#pragma unroll
    for (int mt = 0; mt < 4; mt++)
#pragma unroll
        for (int i = 0; i < 4; i++) {
            float x0 = acc[mt][0][i] * sc0 + sh0;  x0 = (x0 >= 0.f) ? x0 : 0.2f * x0;
            float x1 = acc[mt][1][i] * sc1 + sh1;  x1 = (x1 >= 0.f) ? x1 : 0.2f * x1;
            float pl[6];
#pragma unroll
            for (int s = 0; s < 6; s++) pl[s] = x0 * wc0[s] + x1 * wc1[s];
#pragma unroll
            for (int s = 0; s < 6; s++) {
                pl[s] += __shfl_xor(pl[s], 1);
                pl[s] += __shfl_xor(pl[s], 2);
                pl[s] += __shfl_xor(pl[s], 4);
                pl[s] += __shfl_xor(pl[s], 8);
            }
            if (r16 == 0) {
                int row = mt * 16 + g * 4 + i;
#pragma unroll
                for (int s = 0; s < 6; s++) red[row][wv][s] = pl[s];
            }
        }
    __syncthreads();

    {
        const int lpt = tid >> 3, j = tid & 7;
        float v = -1e30f;
        if (j < 6) {
            v = biasj;
#pragma unroll
            for (int w = 0; w < 8; w++) v += red[lpt][w][j];
        }
        float mx = v;
        mx = fmaxf(mx, __shfl_xor(mx, 1));
        mx = fmaxf(mx, __shfl_xor(mx, 2));
        mx = fmaxf(mx, __shfl_xor(mx, 4));
        float e = (j < 6) ? expf(v - mx) : 0.f;
        float se = e;
        se += __shfl_xor(se, 1);
        se += __shfl_xor(se, 2);
        se += __shfl_xor(se, 4);
        float lsm = v - (mx + logf(se));
        if (lpt < npts) {
            const int pid = plds[lpt];
            float* orow = out + (size_t)pid * OUTK;
            const int gb = ln & 56;
#pragma unroll
            for (int it = 0; it < 7; it++) {
                int k = j + it * 8;
                int jj = k - shc;
                int jc = min(max(jj, 0), 5);
                float val = __shfl(lsm, gb | jc);
                if (k < OUTK)
                    orow[k] = (jj >= 0 && jj < lnc) ? val : 0.f;
            }
        }
    }
}

extern "C" void kernel_launch(void* const* d_in, const int* in_sizes, int n_in,
                              void* d_out, int out_size, void* d_ws, size_t ws_size,
                              hipStream_t stream) {
    const float* F      = (const float*)d_in[0];
    const float* W1     = (const float*)d_in[1];
    const float* gamma  = (const float*)d_in[2];
    const float* beta   = (const float*)d_in[3];
    const float* Wc     = (const float*)d_in[4];
    const float* bias   = (const float*)d_in[5];
    const int*  cats    = (const int*)d_in[6];
    const int*  shifts  = (const int*)d_in[7];
    const int*  seglens = (const int*)d_in[8];
    float* out = (float*)d_out;
    float* ws  = (float*)d_ws;
    u16* Fb  = (u16*)(ws + OFF_FB);
    u16* FbT = (u16*)(ws + OFF_FBT);
    u16* W1T = (u16*)(ws + OFF_W1T);

    int nchunk = 64;
    if (ws_size < ((size_t)OFF_GP + 40960ull * 64) * 4) nchunk = 32;
    if (ws_size < ((size_t)OFF_GP + 40960ull * 32) * 4) nchunk = 16;
    const int Kc = N_PTS / nchunk;

    hipLaunchKernelGGL(k0_cvt,      dim3(2048), dim3(256), 0, stream, F, Fb, FbT);
    hipLaunchKernelGGL(k0b_w1t,     dim3(256),  dim3(256), 0, stream, W1, W1T);
    hipLaunchKernelGGL(k1_gram,     dim3(10 * nchunk), dim3(256), 0, stream, FbT, ws, nchunk, Kc);
    hipLaunchKernelGGL(k1b_colsum,  dim3(256),  dim3(256), 0, stream, FbT, ws);
    hipLaunchKernelGGL(k2a_reduce,  dim3(160),  dim3(256), 0, stream, ws, nchunk);
    hipLaunchKernelGGL(k2b_stats,   dim3(1024), dim3(256), 0, stream, W1, ws);
    hipLaunchKernelGGL(k2c_finish,  dim3(16),   dim3(256), 0, stream, gamma, beta, ws);
    hipLaunchKernelGGL(k3_hist,     dim3(64),   dim3(256), 0, stream, cats, ws);
    hipLaunchKernelGGL(k4_prefix,   dim3(1),    dim3(64),  0, stream, ws);
    hipLaunchKernelGGL(k4b_scatter, dim3(64),   dim3(256), 0, stream, cats, ws);
    hipLaunchKernelGGL(k5_mfma,     dim3(528),  dim3(512), 0, stream,
                       Fb, W1T, Wc, bias, shifts, seglens, ws, out);
}

// Round 11
// 146.468 us; speedup vs baseline: 1.2799x; 1.1313x over previous
//
#include <hip/hip_runtime.h>
#include <hip/hip_bf16.h>
#include <math.h>

#define N_PTS 32768
#define IN_F  256
#define NUM_CAT 16
#define CF    4096
#define NSEG  6
#define OUTK  50
#define BN_EPS 1e-5f

typedef unsigned short u16;
typedef __attribute__((ext_vector_type(8))) short bf16x8;
typedef __attribute__((ext_vector_type(4))) float f32x4;
typedef __attribute__((ext_vector_type(8))) unsigned short u16x8;

// ---- ws layout (float offsets) ----
#define OFF_G     0u          // 256*256
#define OFF_FBAR  65536u      // 256
#define OFF_SCALE 65792u      // 4096
#define OFF_SHIFT 69888u      // 4096
#define OFF_INT   73984u      // int region (33440 ints)
#define OFF_FB    107424u     // F bf16 [32768][256]
#define OFF_FBT   4301728u    // F^T bf16 [256][32768]
#define OFF_W1T   8496032u    // W1T bf16 [16][256 n][256 k]
#define OFF_GP    9020320u    // Gram partials [chunk][40960]
// k2b partials overlay the (dead-after-k2a) GP region:
#define OFF_VP    OFF_GP              // 8 * 4096 floats
#define OFF_MU    (OFF_GP + 32768u)   // 4096 floats
#define IO_COUNTS 0
#define IO_CATOFF 16
#define IO_TILEST 33
#define IO_NTILES 50
#define IO_CURSOR 51
#define IO_ORDER  67
#define IO_TILECAT 32835      // packed: c | (npts-1)<<4 | base<<10   (64-pt tiles)

__device__ __forceinline__ void gload_lds16(const void* g, void* l) {
    __builtin_amdgcn_global_load_lds(
        (const __attribute__((address_space(1))) void*)g,
        (__attribute__((address_space(3))) void*)l,
        16, 0, 0);
}
__device__ __forceinline__ u16 f2bf(float f) {
    unsigned int u = __float_as_uint(f);
    return (u16)((u + 0x7FFF + ((u >> 16) & 1)) >> 16);
}
__device__ __forceinline__ float bf2f(u16 h) {
    return __uint_as_float((unsigned int)h << 16);
}

// ============ K0: F -> Fb (row-major bf16) AND FbT (transposed bf16) ============
__global__ __launch_bounds__(256) void k0_cvt(const float* __restrict__ F,
                                              u16* __restrict__ Fb,
                                              u16* __restrict__ FbT) {
    const int pb = blockIdx.x >> 2, fb = blockIdx.x & 3;
    const int p0 = pb * 64, f0 = fb * 64;
    const int tid = threadIdx.x;
    __shared__ u16 T[64][72];
    {
        int p = tid >> 2, fq = tid & 3;
        const float* src = &F[(size_t)(p0 + p) * IN_F + f0 + fq * 16];
        u16x8 o0, o1;
        float4 v0 = *(const float4*)&src[0];
        float4 v1 = *(const float4*)&src[4];
        float4 v2 = *(const float4*)&src[8];
        float4 v3 = *(const float4*)&src[12];
        o0[0]=f2bf(v0.x); o0[1]=f2bf(v0.y); o0[2]=f2bf(v0.z); o0[3]=f2bf(v0.w);
        o0[4]=f2bf(v1.x); o0[5]=f2bf(v1.y); o0[6]=f2bf(v1.z); o0[7]=f2bf(v1.w);
        o1[0]=f2bf(v2.x); o1[1]=f2bf(v2.y); o1[2]=f2bf(v2.z); o1[3]=f2bf(v2.w);
        o1[4]=f2bf(v3.x); o1[5]=f2bf(v3.y); o1[6]=f2bf(v3.z); o1[7]=f2bf(v3.w);
        u16* dst = &Fb[(size_t)(p0 + p) * IN_F + f0 + fq * 16];
        *(u16x8*)dst = o0; *(u16x8*)&dst[8] = o1;
        *(u16x8*)&T[p][fq * 16] = o0; *(u16x8*)&T[p][fq * 16 + 8] = o1;
    }
    __syncthreads();
    {
        int f = tid >> 2, pq = tid & 3;
        u16x8 a0, a1;
#pragma unroll
        for (int m = 0; m < 8; m++) { a0[m] = T[pq*16 + m][f]; a1[m] = T[pq*16 + 8 + m][f]; }
        u16* dst = &FbT[(size_t)(f0 + f) * N_PTS + p0 + pq * 16];
        *(u16x8*)dst = a0; *(u16x8*)&dst[8] = a1;
    }
}

// ============ K0b: W1 [256][4096] -> W1T bf16 [c][n][k] ============
__global__ __launch_bounds__(256) void k0b_w1t(const float* __restrict__ W1,
                                               u16* __restrict__ W1T) {
    __shared__ u16 T[64][65];
    const int kb = blockIdx.x & 3, jb = blockIdx.x >> 2;
    const int tid = threadIdx.x;
    {
        int kk = tid >> 2, j4 = (tid & 3) * 16;
        const float* src = &W1[(size_t)(kb * 64 + kk) * CF + jb * 64 + j4];
#pragma unroll
        for (int q = 0; q < 4; q++) {
            float4 v = *(const float4*)&src[q * 4];
            T[kk][j4 + q * 4 + 0] = f2bf(v.x); T[kk][j4 + q * 4 + 1] = f2bf(v.y);
            T[kk][j4 + q * 4 + 2] = f2bf(v.z); T[kk][j4 + q * 4 + 3] = f2bf(v.w);
        }
    }
    __syncthreads();
    {
        int jj = tid >> 2, ks = (tid & 3) * 16;
        int c = jb >> 2, n = (jb & 3) * 64 + jj;
        u16* dst = &W1T[((size_t)(c * 256 + n)) * 256 + kb * 64 + ks];
        u16x8 o0, o1;
#pragma unroll
        for (int m = 0; m < 8; m++) { o0[m] = T[ks + m][jj]; o1[m] = T[ks + 8 + m][jj]; }
        *(u16x8*)dst = o0;
        *(u16x8*)&dst[8] = o1;
    }
}

// ============ K1: Gram via bf16 MFMA (10 symmetric tiles x nchunk K-chunks) ============
__global__ __launch_bounds__(256) void k1_gram(const u16* __restrict__ FbT,
                                               float* __restrict__ ws,
                                               int nchunk, int Kc) {
    const int TI[10] = {0,0,0,0,1,1,1,2,2,3};
    const int TJ[10] = {0,1,2,3,1,2,3,2,3,3};
    const int t = blockIdx.x % 10, chunk = blockIdx.x / 10;
    const int i0 = TI[t] * 64, j0 = TJ[t] * 64;
    const int r0 = chunk * Kc;
    const int tid = threadIdx.x;
    const int wv = tid >> 6, ln = tid & 63, g = ln >> 4, r16 = ln & 15;
    __shared__ __align__(16) u16 SA[2][4096];
    __shared__ __align__(16) u16 SB[2][4096];

    const int q0 = wv * 2, q1 = wv * 2 + 1;
    const int u_a = ((q0 * 64 + ln) & 7), row_a = (q0 * 64 + ln) >> 3;
    const int u_b = ((q1 * 64 + ln) & 7), row_b = (q1 * 64 + ln) >> 3;
    const int ka = ((u_a ^ (row_a & 7)) << 3), kb2 = ((u_b ^ (row_b & 7)) << 3);

    f32x4 acc[4];
#pragma unroll
    for (int nt = 0; nt < 4; nt++)
#pragma unroll
        for (int i = 0; i < 4; i++) acc[nt][i] = 0.f;

    const int nslab = Kc >> 6;
#define K1_STAGE(s, b)                                                              \
    {   int p0s = r0 + (s) * 64;                                                    \
        gload_lds16(FbT + (size_t)(i0 + row_a) * N_PTS + p0s + ka,                  \
                    (char*)SA[b] + q0 * 1024);                                      \
        gload_lds16(FbT + (size_t)(i0 + row_b) * N_PTS + p0s + kb2,                 \
                    (char*)SA[b] + q1 * 1024);                                      \
        gload_lds16(FbT + (size_t)(j0 + row_a) * N_PTS + p0s + ka,                  \
                    (char*)SB[b] + q0 * 1024);                                      \
        gload_lds16(FbT + (size_t)(j0 + row_b) * N_PTS + p0s + kb2,                 \
                    (char*)SB[b] + q1 * 1024);                                      \
    }

    K1_STAGE(0, 0);
    __syncthreads();
    for (int s = 0; s < nslab; s++) {
        const int b = s & 1;
        if (s + 1 < nslab) K1_STAGE(s + 1, b ^ 1);
#pragma unroll
        for (int ks = 0; ks < 2; ks++) {
            int ph = (ks * 4 + g) ^ (r16 & 7);
            bf16x8 a = *(const bf16x8*)((const char*)SA[b] + (wv * 16 + r16) * 128 + ph * 16);
#pragma unroll
            for (int nt = 0; nt < 4; nt++) {
                int nB = nt * 16 + r16;
                bf16x8 bb = *(const bf16x8*)((const char*)SB[b] + nB * 128 + ph * 16);
                acc[nt] = __builtin_amdgcn_mfma_f32_16x16x32_bf16(a, bb, acc[nt], 0, 0, 0);
            }
        }
        __syncthreads();
    }
    float* Gp = ws + OFF_GP + (size_t)chunk * 40960 + t * 4096;
#pragma unroll
    for (int nt = 0; nt < 4; nt++)
#pragma unroll
        for (int i = 0; i < 4; i++) {
            int row = wv * 16 + g * 4 + i, col = nt * 16 + r16;
            Gp[row * 64 + col] = acc[nt][i];
        }
}

// ============ K1b: column means from FbT; zero category counts ============
__global__ __launch_bounds__(256) void k1b_colsum(const u16* __restrict__ FbT,
                                                  float* __restrict__ ws) {
    const int row = blockIdx.x, tid = threadIdx.x;
    const u16* r = FbT + (size_t)row * N_PTS;
    float s = 0.f;
    for (int i = tid * 8; i < N_PTS; i += 2048) {
        u16x8 v = *(const u16x8*)&r[i];
#pragma unroll
        for (int m = 0; m < 8; m++) s += bf2f(v[m]);
    }
#pragma unroll
    for (int off = 32; off >= 1; off >>= 1) s += __shfl_xor(s, off);
    __shared__ float ps[4];
    if ((tid & 63) == 0) ps[tid >> 6] = s;
    __syncthreads();
    if (tid == 0) ws[OFF_FBAR + row] = (ps[0] + ps[1] + ps[2] + ps[3]) * (1.0f / N_PTS);
    if (blockIdx.x == 0 && tid < 16) ((int*)(ws + OFF_INT))[IO_COUNTS + tid] = 0;
}

// ============ K2a: coalesced reduce of Gram partials -> symmetric G ============
__global__ __launch_bounds__(256) void k2a_reduce(float* __restrict__ ws, int nchunk) {
    const int TI[10] = {0,0,0,0,1,1,1,2,2,3};
    const int TJ[10] = {0,1,2,3,1,2,3,2,3,3};
    const int e = blockIdx.x * 256 + threadIdx.x;   // 0..40959
    const float* p = ws + OFF_GP + e;
    float s = 0.f;
#pragma unroll 8
    for (int c = 0; c < nchunk; c++) s += p[(size_t)c * 40960];
    int t = e >> 12, x = (e >> 6) & 63, y = e & 63;
    int a = TI[t] * 64 + x, b = TJ[t] * 64 + y;
    ws[OFF_G + a * 256 + b] = s;
    ws[OFF_G + b * 256 + a] = s;
}

// ============ K2b: w^T G w via SGPR-broadcast W1 rows (128 colgrp x 8 b-splits) ====
// acc_j[a] += G[b][a] * w_j[b]: w_j[b] is wave-uniform -> scalar load from fp32 W1
// row b (contiguous in j). Final dots use coalesced bf16 W1T rows. No LDS gather.
__global__ __launch_bounds__(256) void k2b_stats(const float* __restrict__ W1,
                                                 const u16* __restrict__ W1T,
                                                 float* __restrict__ ws) {
    const int tid = threadIdx.x;
    const int jg = blockIdx.x >> 3, sp = blockIdx.x & 7;   // jg 0..127
    const int j0 = jg * 32;
    const int c = jg >> 3, n0 = (jg & 7) * 32;
    __shared__ float pwv[32][4], pwm[32][4];

    float acc[32];
#pragma unroll
    for (int jj = 0; jj < 32; jj++) acc[jj] = 0.f;

    const float* Gs = ws + OFF_G + (size_t)(sp * 32) * 256;
#pragma unroll 2
    for (int b = 0; b < 32; b++) {
        const float g = Gs[b * 256 + tid];              // coalesced vector load
        const float* wrow = W1 + (size_t)(sp * 32 + b) * CF + j0;  // uniform addr
#pragma unroll
        for (int jj = 0; jj < 32; jj++)
            acc[jj] += g * wrow[jj];                    // s_load + v_fma (SGPR src)
    }

    const int lane = tid & 63, wave = tid >> 6;
    const float fb = ws[OFF_FBAR + tid];
#pragma unroll
    for (int jj = 0; jj < 32; jj++) {
        // w_j[k=tid] from W1T row (coalesced 2B loads)
        const float wk = bf2f(W1T[((size_t)(c * 256 + n0 + jj)) * 256 + tid]);
        float v = wk * acc[jj];
#pragma unroll
        for (int off = 32; off >= 1; off >>= 1) v += __shfl_xor(v, off);
        if (lane == 0) pwv[jj][wave] = v;
        if (sp == 0) {
            float m = fb * wk;
#pragma unroll
            for (int off = 32; off >= 1; off >>= 1) m += __shfl_xor(m, off);
            if (lane == 0) pwm[jj][wave] = m;
        }
    }
    __syncthreads();
    if (tid < 32) {
        float v = pwv[tid][0] + pwv[tid][1] + pwv[tid][2] + pwv[tid][3];
        ws[OFF_VP + sp * 4096 + j0 + tid] = v;
        if (sp == 0) {
            float m = pwm[tid][0] + pwm[tid][1] + pwm[tid][2] + pwm[tid][3];
            ws[OFF_MU + j0 + tid] = m;
        }
    }
}

// ============ K2c: combine partials -> scale/shift ============
__global__ __launch_bounds__(256) void k2c_finish(const float* __restrict__ gamma,
                                                  const float* __restrict__ beta,
                                                  float* __restrict__ ws) {
    const int j = blockIdx.x * 256 + threadIdx.x;   // 16 blocks -> 4096
    float v = 0.f;
#pragma unroll
    for (int sp = 0; sp < 8; sp++) v += ws[OFF_VP + sp * 4096 + j];
    const float mu = ws[OFF_MU + j];
    const float var = v * (1.0f / N_PTS) - mu * mu;
    const float sc = gamma[j] * rsqrtf(var + BN_EPS);
    ws[OFF_SCALE + j] = sc;
    ws[OFF_SHIFT + j] = beta[j] - mu * sc;
}

// ============ K3: category histogram ============
__global__ __launch_bounds__(256) void k3_hist(const int* __restrict__ cats,
                                               float* __restrict__ ws) {
    __shared__ int h[16];
    int tid = threadIdx.x;
    if (tid < 16) h[tid] = 0;
    __syncthreads();
    for (int n = blockIdx.x * 256 + tid; n < N_PTS; n += 64 * 256)
        atomicAdd(&h[cats[n]], 1);
    __syncthreads();
    int* wi = (int*)(ws + OFF_INT);
    if (tid < 16) atomicAdd(&wi[IO_COUNTS + tid], h[tid]);
}

// ============ K4: prefix sums + packed per-tile LUT (64-pt tiles) ============
__global__ void k4_prefix(float* __restrict__ ws) {
    int* wi = (int*)(ws + OFF_INT);
    if (threadIdx.x == 0) {
        int co = 0, ts = 0;
        wi[IO_CATOFF] = 0; wi[IO_TILEST] = 0;
        for (int c = 0; c < 16; c++) {
            int cnt = wi[IO_COUNTS + c];
            wi[IO_CURSOR + c] = co;
            int nt = (cnt + 63) >> 6;
            for (int lt = 0; lt < nt; lt++) {
                int npts = min(64, cnt - lt * 64);
                int b = co + lt * 64;
                wi[IO_TILECAT + ts + lt] = c | ((npts - 1) << 4) | (b << 10);
            }
            co += cnt; ts += nt;
            wi[IO_CATOFF + c + 1] = co;
            wi[IO_TILEST + c + 1] = ts;
        }
        wi[IO_NTILES] = ts;
    }
}

// ============ K4b: grouped scatter, two-level (block reservation + LDS ranks) ====
__global__ __launch_bounds__(256) void k4b_scatter(const int* __restrict__ cats,
                                                   float* __restrict__ ws) {
    int* wi = (int*)(ws + OFF_INT);
    __shared__ int lh[16], lbase[16];
    const int tid = threadIdx.x;
    const int n0 = blockIdx.x * 512;
    if (tid < 16) lh[tid] = 0;
    __syncthreads();
    const int cA = cats[n0 + tid];
    const int cB = cats[n0 + 256 + tid];
    atomicAdd(&lh[cA], 1);
    atomicAdd(&lh[cB], 1);
    __syncthreads();
    if (tid < 16) lbase[tid] = atomicAdd(&wi[IO_CURSOR + tid], lh[tid]);
    __syncthreads();
    if (tid < 16) lh[tid] = 0;
    __syncthreads();
    int rA = atomicAdd(&lh[cA], 1);
    wi[IO_ORDER + lbase[cA] + rA] = n0 + tid;
    int rB = atomicAdd(&lh[cB], 1);
    wi[IO_ORDER + lbase[cB] + rB] = n0 + 256 + tid;
}

// ============ K5: bf16-MFMA GEMM — max occupancy, zero K-loop barriers ============
__global__ __launch_bounds__(512, 6) void k5_mfma(const u16* __restrict__ Fb,
                                                  const u16* __restrict__ W1T,
                                                  const float* __restrict__ Wc,
                                                  const float* __restrict__ bias,
                                                  const int* __restrict__ shifts,
                                                  const int* __restrict__ seg_lens,
                                                  const float* __restrict__ ws,
                                                  float* __restrict__ out) {
    const int* wi = (const int*)(ws + OFF_INT);
    const int t = blockIdx.x;
    if (t >= wi[IO_NTILES]) return;
    const unsigned info = (unsigned)wi[IO_TILECAT + t];
    const int c    = info & 15;
    const int npts = ((info >> 4) & 63) + 1;
    const int base = info >> 10;
    const int tid = threadIdx.x;
    const int wv = tid >> 6, ln = tid & 63;
    const int g = ln >> 4, r16 = ln & 15, r7 = r16 & 7;

    __shared__ __align__(16) u16 Fl[16384];     // 32 KB, [64 pt][32 units], ^(pt&7)
    __shared__ float red[64][8][8];             // 16 KB
    __shared__ int plds[64];

    if (tid < 64) plds[tid] = wi[IO_ORDER + base + min(tid, npts - 1)];
    const int col0 = wv * 32 + r16, col1 = col0 + 16;
    const float sc0 = ws[OFF_SCALE + c * 256 + col0];
    const float sc1 = ws[OFF_SCALE + c * 256 + col1];
    const float sh0 = ws[OFF_SHIFT + c * 256 + col0];
    const float sh1 = ws[OFF_SHIFT + c * 256 + col1];
    const float biasj = ((tid & 7) < 6) ? bias[tid & 7] : 0.f;
    const int shc = shifts[c], lnc = seg_lens[c];
    __syncthreads();                            // plds visible

#pragma unroll
    for (int s = 0; s < 4; s++) {
        int flat = (wv * 4 + s) * 64 + ln;
        int pt = flat >> 5, u = flat & 31;
        const u16* src = Fb + (size_t)plds[pt] * 256 + ((u ^ (pt & 7)) << 3);
        gload_lds16(src, (char*)Fl + (size_t)(wv * 4 + s) * 1024);
    }

    const u16* W1Tc = W1T + (size_t)c * 65536;
    const u16* wp0 = W1Tc + (size_t)col0 * 256 + g * 8;
    const u16* wp1 = W1Tc + (size_t)col1 * 256 + g * 8;

    __syncthreads();                            // F resident (vmcnt drained)

    f32x4 acc[4][2];
#pragma unroll
    for (int mt = 0; mt < 4; mt++)
#pragma unroll
        for (int nt = 0; nt < 2; nt++)
#pragma unroll
            for (int i = 0; i < 4; i++) acc[mt][nt][i] = 0.f;

    bf16x8 bf0[2], bf1[2];
    bf0[0] = *(const bf16x8*)(wp0);
    bf1[0] = *(const bf16x8*)(wp1);

#pragma unroll
    for (int kc = 0; kc < 8; kc++) {
        if (kc < 7) {
            bf0[(kc + 1) & 1] = *(const bf16x8*)(wp0 + (kc + 1) * 32);
            bf1[(kc + 1) & 1] = *(const bf16x8*)(wp1 + (kc + 1) * 32);
        }
#pragma unroll
        for (int mt = 0; mt < 4; mt++) {
            int row = mt * 16 + r16;
            int ph = ((kc * 4 + g) ^ r7) * 16;
            bf16x8 af = *(const bf16x8*)((const char*)Fl + (size_t)row * 512 + ph);
            acc[mt][0] = __builtin_amdgcn_mfma_f32_16x16x32_bf16(af, bf0[kc & 1], acc[mt][0], 0, 0, 0);
            acc[mt][1] = __builtin_amdgcn_mfma_f32_16x16x32_bf16(af, bf1[kc & 1], acc[mt][1], 0, 0, 0);
        }
    }
    __builtin_amdgcn_sched_barrier(0);

    float wc0[6], wc1[6];
#pragma unroll
    for (int s = 0; s < 6; s++) {
        wc0[s] = Wc[(size_t)c * 1536 + col0 * 6 + s];
        wc1[s] = Wc[(size_t)c * 1536 + col1 * 6 + s];
    }
#pragma unroll
    for (int mt = 0; mt < 4; mt++)
#pragma unroll
        for (int i = 0; i < 4; i++) {
            float x0 = acc[mt][0][i] * sc0 + sh0;  x0 = (x0 >= 0.f) ? x0 : 0.2f * x0;
            float x1 = acc[mt][1][i] * sc1 + sh1;  x1 = (x1 >= 0.f) ? x1 : 0.2f * x1;
            float pl[6];
#pragma unroll
            for (int s = 0; s < 6; s++) pl[s] = x0 * wc0[s] + x1 * wc1[s];
#pragma unroll
            for (int s = 0; s < 6; s++) {
                pl[s] += __shfl_xor(pl[s], 1);
                pl[s] += __shfl_xor(pl[s], 2);
                pl[s] += __shfl_xor(pl[s], 4);
                pl[s] += __shfl_xor(pl[s], 8);
            }
            if (r16 == 0) {
                int row = mt * 16 + g * 4 + i;
#pragma unroll
                for (int s = 0; s < 6; s++) red[row][wv][s] = pl[s];
            }
        }
    __syncthreads();

    {
        const int lpt = tid >> 3, j = tid & 7;
        float v = -1e30f;
        if (j < 6) {
            v = biasj;
#pragma unroll
            for (int w = 0; w < 8; w++) v += red[lpt][w][j];
        }
        float mx = v;
        mx = fmaxf(mx, __shfl_xor(mx, 1));
        mx = fmaxf(mx, __shfl_xor(mx, 2));
        mx = fmaxf(mx, __shfl_xor(mx, 4));
        float e = (j < 6) ? expf(v - mx) : 0.f;
        float se = e;
        se += __shfl_xor(se, 1);
        se += __shfl_xor(se, 2);
        se += __shfl_xor(se, 4);
        float lsm = v - (mx + logf(se));
        if (lpt < npts) {
            const int pid = plds[lpt];
            float* orow = out + (size_t)pid * OUTK;
            const int gb = ln & 56;
#pragma unroll
            for (int it = 0; it < 7; it++) {
                int k = j + it * 8;
                int jj = k - shc;
                int jc = min(max(jj, 0), 5);
                float val = __shfl(lsm, gb | jc);
                if (k < OUTK)
                    orow[k] = (jj >= 0 && jj < lnc) ? val : 0.f;
            }
        }
    }
}

extern "C" void kernel_launch(void* const* d_in, const int* in_sizes, int n_in,
                              void* d_out, int out_size, void* d_ws, size_t ws_size,
                              hipStream_t stream) {
    const float* F      = (const float*)d_in[0];
    const float* W1     = (const float*)d_in[1];
    const float* gamma  = (const float*)d_in[2];
    const float* beta   = (const float*)d_in[3];
    const float* Wc     = (const float*)d_in[4];
    const float* bias   = (const float*)d_in[5];
    const int*  cats    = (const int*)d_in[6];
    const int*  shifts  = (const int*)d_in[7];
    const int*  seglens = (const int*)d_in[8];
    float* out = (float*)d_out;
    float* ws  = (float*)d_ws;
    u16* Fb  = (u16*)(ws + OFF_FB);
    u16* FbT = (u16*)(ws + OFF_FBT);
    u16* W1T = (u16*)(ws + OFF_W1T);

    int nchunk = 64;
    if (ws_size < ((size_t)OFF_GP + 40960ull * 64) * 4) nchunk = 32;
    if (ws_size < ((size_t)OFF_GP + 40960ull * 32) * 4) nchunk = 16;
    const int Kc = N_PTS / nchunk;

    hipLaunchKernelGGL(k0_cvt,      dim3(2048), dim3(256), 0, stream, F, Fb, FbT);
    hipLaunchKernelGGL(k0b_w1t,     dim3(256),  dim3(256), 0, stream, W1, W1T);
    hipLaunchKernelGGL(k1_gram,     dim3(10 * nchunk), dim3(256), 0, stream, FbT, ws, nchunk, Kc);
    hipLaunchKernelGGL(k1b_colsum,  dim3(256),  dim3(256), 0, stream, FbT, ws);
    hipLaunchKernelGGL(k2a_reduce,  dim3(160),  dim3(256), 0, stream, ws, nchunk);
    hipLaunchKernelGGL(k2b_stats,   dim3(1024), dim3(256), 0, stream, W1, W1T, ws);
    hipLaunchKernelGGL(k2c_finish,  dim3(16),   dim3(256), 0, stream, gamma, beta, ws);
    hipLaunchKernelGGL(k3_hist,     dim3(64),   dim3(256), 0, stream, cats, ws);
    hipLaunchKernelGGL(k4_prefix,   dim3(1),    dim3(64),  0, stream, ws);
    hipLaunchKernelGGL(k4b_scatter, dim3(64),   dim3(256), 0, stream, cats, ws);
    hipLaunchKernelGGL(k5_mfma,     dim3(528),  dim3(512), 0, stream,
                       Fb, W1T, Wc, bias, shifts, seglens, ws, out);
}

// Round 12
// 145.719 us; speedup vs baseline: 1.2865x; 1.0051x over previous
//
#include <hip/hip_runtime.h>
#include <hip/hip_bf16.h>
#include <math.h>

#define N_PTS 32768
#define IN_F  256
#define NUM_CAT 16
#define CF    4096
#define NSEG  6
#define OUTK  50
#define BN_EPS 1e-5f

typedef unsigned short u16;
typedef __attribute__((ext_vector_type(8))) short bf16x8;
typedef __attribute__((ext_vector_type(4))) float f32x4;
typedef __attribute__((ext_vector_type(8))) unsigned short u16x8;

// ---- ws layout (float offsets) ----
#define OFF_G     0u          // 256*256
#define OFF_FBAR  65536u      // 256
#define OFF_SCALE 65792u      // 4096
#define OFF_SHIFT 69888u      // 4096
#define OFF_INT   73984u      // int region (33440 ints)
#define OFF_FB    107424u     // F bf16 [32768][256]
#define OFF_FBT   4301728u    // F^T bf16 [256][32768]
#define OFF_W1T   8496032u    // W1T bf16 [16][256 n][256 k]
#define OFF_GP    9020320u    // Gram partials [chunk][40960]
// k2b partials overlay the (dead-after-k2a) GP region:
#define OFF_VP    OFF_GP              // 8 * 4096 floats
#define OFF_MU    (OFF_GP + 32768u)   // 4096 floats
#define IO_COUNTS 0
#define IO_CATOFF 16
#define IO_TILEST 33
#define IO_NTILES 50
#define IO_CURSOR 51
#define IO_ORDER  67
#define IO_TILECAT 32835      // packed: c | (npts-1)<<4 | base<<10   (64-pt tiles)

__device__ __forceinline__ void gload_lds16(const void* g, void* l) {
    __builtin_amdgcn_global_load_lds(
        (const __attribute__((address_space(1))) void*)g,
        (__attribute__((address_space(3))) void*)l,
        16, 0, 0);
}
__device__ __forceinline__ u16 f2bf(float f) {
    unsigned int u = __float_as_uint(f);
    return (u16)((u + 0x7FFF + ((u >> 16) & 1)) >> 16);
}
__device__ __forceinline__ float bf2f(u16 h) {
    return __uint_as_float((unsigned int)h << 16);
}

// ============ K0: F -> Fb (row-major bf16) AND FbT (transposed bf16) ============
__global__ __launch_bounds__(256) void k0_cvt(const float* __restrict__ F,
                                              u16* __restrict__ Fb,
                                              u16* __restrict__ FbT) {
    const int pb = blockIdx.x >> 2, fb = blockIdx.x & 3;
    const int p0 = pb * 64, f0 = fb * 64;
    const int tid = threadIdx.x;
    __shared__ u16 T[64][72];
    {
        int p = tid >> 2, fq = tid & 3;
        const float* src = &F[(size_t)(p0 + p) * IN_F + f0 + fq * 16];
        u16x8 o0, o1;
        float4 v0 = *(const float4*)&src[0];
        float4 v1 = *(const float4*)&src[4];
        float4 v2 = *(const float4*)&src[8];
        float4 v3 = *(const float4*)&src[12];
        o0[0]=f2bf(v0.x); o0[1]=f2bf(v0.y); o0[2]=f2bf(v0.z); o0[3]=f2bf(v0.w);
        o0[4]=f2bf(v1.x); o0[5]=f2bf(v1.y); o0[6]=f2bf(v1.z); o0[7]=f2bf(v1.w);
        o1[0]=f2bf(v2.x); o1[1]=f2bf(v2.y); o1[2]=f2bf(v2.z); o1[3]=f2bf(v2.w);
        o1[4]=f2bf(v3.x); o1[5]=f2bf(v3.y); o1[6]=f2bf(v3.z); o1[7]=f2bf(v3.w);
        u16* dst = &Fb[(size_t)(p0 + p) * IN_F + f0 + fq * 16];
        *(u16x8*)dst = o0; *(u16x8*)&dst[8] = o1;
        *(u16x8*)&T[p][fq * 16] = o0; *(u16x8*)&T[p][fq * 16 + 8] = o1;
    }
    __syncthreads();
    {
        int f = tid >> 2, pq = tid & 3;
        u16x8 a0, a1;
#pragma unroll
        for (int m = 0; m < 8; m++) { a0[m] = T[pq*16 + m][f]; a1[m] = T[pq*16 + 8 + m][f]; }
        u16* dst = &FbT[(size_t)(f0 + f) * N_PTS + p0 + pq * 16];
        *(u16x8*)dst = a0; *(u16x8*)&dst[8] = a1;
    }
}

// ============ K0b: W1 [256][4096] -> W1T bf16 [c][n][k] ============
__global__ __launch_bounds__(256) void k0b_w1t(const float* __restrict__ W1,
                                               u16* __restrict__ W1T) {
    __shared__ u16 T[64][65];
    const int kb = blockIdx.x & 3, jb = blockIdx.x >> 2;
    const int tid = threadIdx.x;
    {
        int kk = tid >> 2, j4 = (tid & 3) * 16;
        const float* src = &W1[(size_t)(kb * 64 + kk) * CF + jb * 64 + j4];
#pragma unroll
        for (int q = 0; q < 4; q++) {
            float4 v = *(const float4*)&src[q * 4];
            T[kk][j4 + q * 4 + 0] = f2bf(v.x); T[kk][j4 + q * 4 + 1] = f2bf(v.y);
            T[kk][j4 + q * 4 + 2] = f2bf(v.z); T[kk][j4 + q * 4 + 3] = f2bf(v.w);
        }
    }
    __syncthreads();
    {
        int jj = tid >> 2, ks = (tid & 3) * 16;
        int c = jb >> 2, n = (jb & 3) * 64 + jj;
        u16* dst = &W1T[((size_t)(c * 256 + n)) * 256 + kb * 64 + ks];
        u16x8 o0, o1;
#pragma unroll
        for (int m = 0; m < 8; m++) { o0[m] = T[ks + m][jj]; o1[m] = T[ks + 8 + m][jj]; }
        *(u16x8*)dst = o0;
        *(u16x8*)&dst[8] = o1;
    }
}

// ============ K1: Gram via bf16 MFMA (10 symmetric tiles x nchunk K-chunks) ============
__global__ __launch_bounds__(256) void k1_gram(const u16* __restrict__ FbT,
                                               float* __restrict__ ws,
                                               int nchunk, int Kc) {
    const int TI[10] = {0,0,0,0,1,1,1,2,2,3};
    const int TJ[10] = {0,1,2,3,1,2,3,2,3,3};
    const int t = blockIdx.x % 10, chunk = blockIdx.x / 10;
    const int i0 = TI[t] * 64, j0 = TJ[t] * 64;
    const int r0 = chunk * Kc;
    const int tid = threadIdx.x;
    const int wv = tid >> 6, ln = tid & 63, g = ln >> 4, r16 = ln & 15;
    __shared__ __align__(16) u16 SA[2][4096];
    __shared__ __align__(16) u16 SB[2][4096];

    const int q0 = wv * 2, q1 = wv * 2 + 1;
    const int u_a = ((q0 * 64 + ln) & 7), row_a = (q0 * 64 + ln) >> 3;
    const int u_b = ((q1 * 64 + ln) & 7), row_b = (q1 * 64 + ln) >> 3;
    const int ka = ((u_a ^ (row_a & 7)) << 3), kb2 = ((u_b ^ (row_b & 7)) << 3);

    f32x4 acc[4];
#pragma unroll
    for (int nt = 0; nt < 4; nt++)
#pragma unroll
        for (int i = 0; i < 4; i++) acc[nt][i] = 0.f;

    const int nslab = Kc >> 6;
#define K1_STAGE(s, b)                                                              \
    {   int p0s = r0 + (s) * 64;                                                    \
        gload_lds16(FbT + (size_t)(i0 + row_a) * N_PTS + p0s + ka,                  \
                    (char*)SA[b] + q0 * 1024);                                      \
        gload_lds16(FbT + (size_t)(i0 + row_b) * N_PTS + p0s + kb2,                 \
                    (char*)SA[b] + q1 * 1024);                                      \
        gload_lds16(FbT + (size_t)(j0 + row_a) * N_PTS + p0s + ka,                  \
                    (char*)SB[b] + q0 * 1024);                                      \
        gload_lds16(FbT + (size_t)(j0 + row_b) * N_PTS + p0s + kb2,                 \
                    (char*)SB[b] + q1 * 1024);                                      \
    }

    K1_STAGE(0, 0);
    __syncthreads();
    for (int s = 0; s < nslab; s++) {
        const int b = s & 1;
        if (s + 1 < nslab) K1_STAGE(s + 1, b ^ 1);
#pragma unroll
        for (int ks = 0; ks < 2; ks++) {
            int ph = (ks * 4 + g) ^ (r16 & 7);
            bf16x8 a = *(const bf16x8*)((const char*)SA[b] + (wv * 16 + r16) * 128 + ph * 16);
#pragma unroll
            for (int nt = 0; nt < 4; nt++) {
                int nB = nt * 16 + r16;
                bf16x8 bb = *(const bf16x8*)((const char*)SB[b] + nB * 128 + ph * 16);
                acc[nt] = __builtin_amdgcn_mfma_f32_16x16x32_bf16(a, bb, acc[nt], 0, 0, 0);
            }
        }
        __syncthreads();
    }
    float* Gp = ws + OFF_GP + (size_t)chunk * 40960 + t * 4096;
#pragma unroll
    for (int nt = 0; nt < 4; nt++)
#pragma unroll
        for (int i = 0; i < 4; i++) {
            int row = wv * 16 + g * 4 + i, col = nt * 16 + r16;
            Gp[row * 64 + col] = acc[nt][i];
        }
}

// ============ K1b: column means from FbT; zero category counts ============
__global__ __launch_bounds__(256) void k1b_colsum(const u16* __restrict__ FbT,
                                                  float* __restrict__ ws) {
    const int row = blockIdx.x, tid = threadIdx.x;
    const u16* r = FbT + (size_t)row * N_PTS;
    float s = 0.f;
    for (int i = tid * 8; i < N_PTS; i += 2048) {
        u16x8 v = *(const u16x8*)&r[i];
#pragma unroll
        for (int m = 0; m < 8; m++) s += bf2f(v[m]);
    }
#pragma unroll
    for (int off = 32; off >= 1; off >>= 1) s += __shfl_xor(s, off);
    __shared__ float ps[4];
    if ((tid & 63) == 0) ps[tid >> 6] = s;
    __syncthreads();
    if (tid == 0) ws[OFF_FBAR + row] = (ps[0] + ps[1] + ps[2] + ps[3]) * (1.0f / N_PTS);
    if (blockIdx.x == 0 && tid < 16) ((int*)(ws + OFF_INT))[IO_COUNTS + tid] = 0;
}

// ============ K2a: coalesced reduce of Gram partials -> symmetric G ============
__global__ __launch_bounds__(256) void k2a_reduce(float* __restrict__ ws, int nchunk) {
    const int TI[10] = {0,0,0,0,1,1,1,2,2,3};
    const int TJ[10] = {0,1,2,3,1,2,3,2,3,3};
    const int e = blockIdx.x * 256 + threadIdx.x;   // 0..40959
    const float* p = ws + OFF_GP + e;
    float s = 0.f;
#pragma unroll 8
    for (int c = 0; c < nchunk; c++) s += p[(size_t)c * 40960];
    int t = e >> 12, x = (e >> 6) & 63, y = e & 63;
    int a = TI[t] * 64 + x, b = TJ[t] * 64 + y;
    ws[OFF_G + a * 256 + b] = s;
    ws[OFF_G + b * 256 + a] = s;
}

// ============ K2b: w^T G w via SGPR-broadcast W1 rows (128 colgrp x 8 b-splits) ====
__global__ __launch_bounds__(256) void k2b_stats(const float* __restrict__ W1,
                                                 const u16* __restrict__ W1T,
                                                 float* __restrict__ ws) {
    const int tid = threadIdx.x;
    const int jg = blockIdx.x >> 3, sp = blockIdx.x & 7;   // jg 0..127
    const int j0 = jg * 32;
    const int c = jg >> 3, n0 = (jg & 7) * 32;
    __shared__ float pwv[32][4], pwm[32][4];

    float acc[32];
#pragma unroll
    for (int jj = 0; jj < 32; jj++) acc[jj] = 0.f;

    const float* Gs = ws + OFF_G + (size_t)(sp * 32) * 256;
#pragma unroll 2
    for (int b = 0; b < 32; b++) {
        const float g = Gs[b * 256 + tid];              // coalesced vector load
        const float* wrow = W1 + (size_t)(sp * 32 + b) * CF + j0;  // uniform addr
#pragma unroll
        for (int jj = 0; jj < 32; jj++)
            acc[jj] += g * wrow[jj];                    // s_load + v_fma (SGPR src)
    }

    const int lane = tid & 63, wave = tid >> 6;
    const float fb = ws[OFF_FBAR + tid];
#pragma unroll
    for (int jj = 0; jj < 32; jj++) {
        const float wk = bf2f(W1T[((size_t)(c * 256 + n0 + jj)) * 256 + tid]);
        float v = wk * acc[jj];
#pragma unroll
        for (int off = 32; off >= 1; off >>= 1) v += __shfl_xor(v, off);
        if (lane == 0) pwv[jj][wave] = v;
        if (sp == 0) {
            float m = fb * wk;
#pragma unroll
            for (int off = 32; off >= 1; off >>= 1) m += __shfl_xor(m, off);
            if (lane == 0) pwm[jj][wave] = m;
        }
    }
    __syncthreads();
    if (tid < 32) {
        float v = pwv[tid][0] + pwv[tid][1] + pwv[tid][2] + pwv[tid][3];
        ws[OFF_VP + sp * 4096 + j0 + tid] = v;
        if (sp == 0) {
            float m = pwm[tid][0] + pwm[tid][1] + pwm[tid][2] + pwm[tid][3];
            ws[OFF_MU + j0 + tid] = m;
        }
    }
}

// ============ K2c: combine partials -> scale/shift ============
__global__ __launch_bounds__(256) void k2c_finish(const float* __restrict__ gamma,
                                                  const float* __restrict__ beta,
                                                  float* __restrict__ ws) {
    const int j = blockIdx.x * 256 + threadIdx.x;   // 16 blocks -> 4096
    float v = 0.f;
#pragma unroll
    for (int sp = 0; sp < 8; sp++) v += ws[OFF_VP + sp * 4096 + j];
    const float mu = ws[OFF_MU + j];
    const float var = v * (1.0f / N_PTS) - mu * mu;
    const float sc = gamma[j] * rsqrtf(var + BN_EPS);
    ws[OFF_SCALE + j] = sc;
    ws[OFF_SHIFT + j] = beta[j] - mu * sc;
}

// ============ K3: category histogram ============
__global__ __launch_bounds__(256) void k3_hist(const int* __restrict__ cats,
                                               float* __restrict__ ws) {
    __shared__ int h[16];
    int tid = threadIdx.x;
    if (tid < 16) h[tid] = 0;
    __syncthreads();
    for (int n = blockIdx.x * 256 + tid; n < N_PTS; n += 64 * 256)
        atomicAdd(&h[cats[n]], 1);
    __syncthreads();
    int* wi = (int*)(ws + OFF_INT);
    if (tid < 16) atomicAdd(&wi[IO_COUNTS + tid], h[tid]);
}

// ============ K4: prefix sums + packed per-tile LUT (64-pt tiles) ============
__global__ void k4_prefix(float* __restrict__ ws) {
    int* wi = (int*)(ws + OFF_INT);
    if (threadIdx.x == 0) {
        int co = 0, ts = 0;
        wi[IO_CATOFF] = 0; wi[IO_TILEST] = 0;
        for (int c = 0; c < 16; c++) {
            int cnt = wi[IO_COUNTS + c];
            wi[IO_CURSOR + c] = co;
            int nt = (cnt + 63) >> 6;
            for (int lt = 0; lt < nt; lt++) {
                int npts = min(64, cnt - lt * 64);
                int b = co + lt * 64;
                wi[IO_TILECAT + ts + lt] = c | ((npts - 1) << 4) | (b << 10);
            }
            co += cnt; ts += nt;
            wi[IO_CATOFF + c + 1] = co;
            wi[IO_TILEST + c + 1] = ts;
        }
        wi[IO_NTILES] = ts;
    }
}

// ============ K4b: grouped scatter, two-level (block reservation + LDS ranks) ====
__global__ __launch_bounds__(256) void k4b_scatter(const int* __restrict__ cats,
                                                   float* __restrict__ ws) {
    int* wi = (int*)(ws + OFF_INT);
    __shared__ int lh[16], lbase[16];
    const int tid = threadIdx.x;
    const int n0 = blockIdx.x * 512;
    if (tid < 16) lh[tid] = 0;
    __syncthreads();
    const int cA = cats[n0 + tid];
    const int cB = cats[n0 + 256 + tid];
    atomicAdd(&lh[cA], 1);
    atomicAdd(&lh[cB], 1);
    __syncthreads();
    if (tid < 16) lbase[tid] = atomicAdd(&wi[IO_CURSOR + tid], lh[tid]);
    __syncthreads();
    if (tid < 16) lh[tid] = 0;
    __syncthreads();
    int rA = atomicAdd(&lh[cA], 1);
    wi[IO_ORDER + lbase[cA] + rA] = n0 + tid;
    int rB = atomicAdd(&lh[cB], 1);
    wi[IO_ORDER + lbase[cB] + rB] = n0 + 256 + tid;
}

// ============ K5: bf16-MFMA GEMM — all W fragments resident in registers ============
// 64 pts x 256 cols, 512 thr / 8 waves. F tile in LDS (staged once, swizzled).
// Each thread holds its ENTIRE W slice (16 x bf16x8 = 64 VGPR), all loads issued
// before the single barrier -> one overlapped latency window; K-loop is pure
// MFMA + ds_read, zero vmcnt waits.
__global__ __launch_bounds__(512, 4) void k5_mfma(const u16* __restrict__ Fb,
                                                  const u16* __restrict__ W1T,
                                                  const float* __restrict__ Wc,
                                                  const float* __restrict__ bias,
                                                  const int* __restrict__ shifts,
                                                  const int* __restrict__ seg_lens,
                                                  const float* __restrict__ ws,
                                                  float* __restrict__ out) {
    const int* wi = (const int*)(ws + OFF_INT);
    const int t = blockIdx.x;
    if (t >= wi[IO_NTILES]) return;
    const unsigned info = (unsigned)wi[IO_TILECAT + t];
    const int c    = info & 15;
    const int npts = ((info >> 4) & 63) + 1;
    const int base = info >> 10;
    const int tid = threadIdx.x;
    const int wv = tid >> 6, ln = tid & 63;
    const int g = ln >> 4, r16 = ln & 15, r7 = r16 & 7;

    __shared__ __align__(16) u16 Fl[16384];     // 32 KB, [64 pt][32 units], ^(pt&7)
    __shared__ float red[64][8][8];             // 16 KB
    __shared__ int plds[64];

    if (tid < 64) plds[tid] = wi[IO_ORDER + base + min(tid, npts - 1)];
    const int col0 = wv * 32 + r16, col1 = col0 + 16;
    const float sc0 = ws[OFF_SCALE + c * 256 + col0];
    const float sc1 = ws[OFF_SCALE + c * 256 + col1];
    const float sh0 = ws[OFF_SHIFT + c * 256 + col0];
    const float sh1 = ws[OFF_SHIFT + c * 256 + col1];
    const float biasj = ((tid & 7) < 6) ? bias[tid & 7] : 0.f;
    const int shc = shifts[c], lnc = seg_lens[c];
    __syncthreads();                            // plds visible

    // ---- issue F staging (uses plds) ----
#pragma unroll
    for (int s = 0; s < 4; s++) {
        int flat = (wv * 4 + s) * 64 + ln;
        int pt = flat >> 5, u = flat & 31;
        const u16* src = Fb + (size_t)plds[pt] * 256 + ((u ^ (pt & 7)) << 3);
        gload_lds16(src, (char*)Fl + (size_t)(wv * 4 + s) * 1024);
    }

    // ---- issue ALL W loads into registers (64 VGPR), overlapping F latency ----
    const u16* W1Tc = W1T + (size_t)c * 65536;
    const u16* wp0 = W1Tc + (size_t)col0 * 256 + g * 8;
    const u16* wp1 = W1Tc + (size_t)col1 * 256 + g * 8;
    bf16x8 w0[8], w1[8];
#pragma unroll
    for (int kc = 0; kc < 8; kc++) {
        w0[kc] = *(const bf16x8*)(wp0 + kc * 32);
        w1[kc] = *(const bf16x8*)(wp1 + kc * 32);
    }
    __builtin_amdgcn_sched_barrier(0);          // pin load block before barrier

    __syncthreads();                            // drains vmcnt: F + all W ready

    f32x4 acc[4][2];
#pragma unroll
    for (int mt = 0; mt < 4; mt++)
#pragma unroll
        for (int nt = 0; nt < 2; nt++)
#pragma unroll
            for (int i = 0; i < 4; i++) acc[mt][nt][i] = 0.f;

#pragma unroll
    for (int kc = 0; kc < 8; kc++) {
#pragma unroll
        for (int mt = 0; mt < 4; mt++) {
            int row = mt * 16 + r16;
            int ph = ((kc * 4 + g) ^ r7) * 16;
            bf16x8 af = *(const bf16x8*)((const char*)Fl + (size_t)row * 512 + ph);
            acc[mt][0] = __builtin_amdgcn_mfma_f32_16x16x32_bf16(af, w0[kc], acc[mt][0], 0, 0, 0);
            acc[mt][1] = __builtin_amdgcn_mfma_f32_16x16x32_bf16(af, w1[kc], acc[mt][1], 0, 0, 0);
        }
    }
    __builtin_amdgcn_sched_barrier(0);          // keep Wc loads out of K-loop

    float wc0[6], wc1[6];
#pragma unroll
    for (int s = 0; s < 6; s++) {
        wc0[s] = Wc[(size_t)c * 1536 + col0 * 6 + s];
        wc1[s] = Wc[(size_t)c * 1536 + col1 * 6 + s];
    }
#pragma unroll
    for (int mt = 0; mt < 4; mt++)
#pragma unroll
        for (int i = 0; i < 4; i++) {
            float x0 = acc[mt][0][i] * sc0 + sh0;  x0 = (x0 >= 0.f) ? x0 : 0.2f * x0;
            float x1 = acc[mt][1][i] * sc1 + sh1;  x1 = (x1 >= 0.f) ? x1 : 0.2f * x1;
            float pl[6];
#pragma unroll
            for (int s = 0; s < 6; s++) pl[s] = x0 * wc0[s] + x1 * wc1[s];
#pragma unroll
            for (int s = 0; s < 6; s++) {
                pl[s] += __shfl_xor(pl[s], 1);
                pl[s] += __shfl_xor(pl[s], 2);
                pl[s] += __shfl_xor(pl[s], 4);
                pl[s] += __shfl_xor(pl[s], 8);
            }
            if (r16 == 0) {
                int row = mt * 16 + g * 4 + i;
#pragma unroll
                for (int s = 0; s < 6; s++) red[row][wv][s] = pl[s];
            }
        }
    __syncthreads();

    {
        const int lpt = tid >> 3, j = tid & 7;
        float v = -1e30f;
        if (j < 6) {
            v = biasj;
#pragma unroll
            for (int w = 0; w < 8; w++) v += red[lpt][w][j];
        }
        float mx = v;
        mx = fmaxf(mx, __shfl_xor(mx, 1));
        mx = fmaxf(mx, __shfl_xor(mx, 2));
        mx = fmaxf(mx, __shfl_xor(mx, 4));
        float e = (j < 6) ? expf(v - mx) : 0.f;
        float se = e;
        se += __shfl_xor(se, 1);
        se += __shfl_xor(se, 2);
        se += __shfl_xor(se, 4);
        float lsm = v - (mx + logf(se));
        if (lpt < npts) {
            const int pid = plds[lpt];
            float* orow = out + (size_t)pid * OUTK;
            const int gb = ln & 56;
#pragma unroll
            for (int it = 0; it < 7; it++) {
                int k = j + it * 8;
                int jj = k - shc;
                int jc = min(max(jj, 0), 5);
                float val = __shfl(lsm, gb | jc);
                if (k < OUTK)
                    orow[k] = (jj >= 0 && jj < lnc) ? val : 0.f;
            }
        }
    }
}

extern "C" void kernel_launch(void* const* d_in, const int* in_sizes, int n_in,
                              void* d_out, int out_size, void* d_ws, size_t ws_size,
                              hipStream_t stream) {
    const float* F      = (const float*)d_in[0];
    const float* W1     = (const float*)d_in[1];
    const float* gamma  = (const float*)d_in[2];
    const float* beta   = (const float*)d_in[3];
    const float* Wc     = (const float*)d_in[4];
    const float* bias   = (const float*)d_in[5];
    const int*  cats    = (const int*)d_in[6];
    const int*  shifts  = (const int*)d_in[7];
    const int*  seglens = (const int*)d_in[8];
    float* out = (float*)d_out;
    float* ws  = (float*)d_ws;
    u16* Fb  = (u16*)(ws + OFF_FB);
    u16* FbT = (u16*)(ws + OFF_FBT);
    u16* W1T = (u16*)(ws + OFF_W1T);

    int nchunk = 64;
    if (ws_size < ((size_t)OFF_GP + 40960ull * 64) * 4) nchunk = 32;
    if (ws_size < ((size_t)OFF_GP + 40960ull * 32) * 4) nchunk = 16;
    const int Kc = N_PTS / nchunk;

    hipLaunchKernelGGL(k0_cvt,      dim3(2048), dim3(256), 0, stream, F, Fb, FbT);
    hipLaunchKernelGGL(k0b_w1t,     dim3(256),  dim3(256), 0, stream, W1, W1T);
    hipLaunchKernelGGL(k1_gram,     dim3(10 * nchunk), dim3(256), 0, stream, FbT, ws, nchunk, Kc);
    hipLaunchKernelGGL(k1b_colsum,  dim3(256),  dim3(256), 0, stream, FbT, ws);
    hipLaunchKernelGGL(k2a_reduce,  dim3(160),  dim3(256), 0, stream, ws, nchunk);
    hipLaunchKernelGGL(k2b_stats,   dim3(1024), dim3(256), 0, stream, W1, W1T, ws);
    hipLaunchKernelGGL(k2c_finish,  dim3(16),   dim3(256), 0, stream, gamma, beta, ws);
    hipLaunchKernelGGL(k3_hist,     dim3(64),   dim3(256), 0, stream, cats, ws);
    hipLaunchKernelGGL(k4_prefix,   dim3(1),    dim3(64),  0, stream, ws);
    hipLaunchKernelGGL(k4b_scatter, dim3(64),   dim3(256), 0, stream, cats, ws);
    hipLaunchKernelGGL(k5_mfma,     dim3(528),  dim3(512), 0, stream,
                       Fb, W1T, Wc, bias, shifts, seglens, ws, out);
}

// Round 13
// 124.324 us; speedup vs baseline: 1.5079x; 1.1721x over previous
//
#include <hip/hip_runtime.h>
#include <hip/hip_bf16.h>
#include <math.h>

#define N_PTS 32768
#define IN_F  256
#define NUM_CAT 16
#define CF    4096
#define NSEG  6
#define OUTK  50
#define BN_EPS 1e-5f

typedef unsigned short u16;
typedef __attribute__((ext_vector_type(8))) short bf16x8;
typedef __attribute__((ext_vector_type(4))) float f32x4;
typedef __attribute__((ext_vector_type(8))) unsigned short u16x8;

// ---- ws layout (float offsets) ----
#define OFF_G     0u          // 256*256
#define OFF_FBAR  65536u      // 256
#define OFF_SCALE 65792u      // 4096
#define OFF_SHIFT 69888u      // 4096
#define OFF_INT   73984u      // int region (33440 ints)
#define OFF_FB    107424u     // F bf16 [32768][256]
#define OFF_FBT   4301728u    // F^T bf16 [256][32768]
#define OFF_W1T   8496032u    // W1T bf16 [16][256 n][256 k]
#define OFF_GP    9020320u    // Gram partials [chunk][49152] (3 tiles x 128x128)
// k2b partials overlay the (dead-after-k2a) GP region:
#define OFF_VP    OFF_GP              // 8 * 4096 floats
#define OFF_MU    (OFF_GP + 32768u)   // 4096 floats
// int offsets (ints, rel OFF_INT)
#define IO_CATOFF 16          // 17 ints
#define IO_ORDER  67          // 32768 ints
#define IO_PC     32835       // u16[64][16] = 512 ints -> ends 33347 (<33440)

__device__ __forceinline__ void gload_lds16(const void* g, void* l) {
    __builtin_amdgcn_global_load_lds(
        (const __attribute__((address_space(1))) void*)g,
        (__attribute__((address_space(3))) void*)l,
        16, 0, 0);
}
__device__ __forceinline__ u16 f2bf(float f) {
    unsigned int u = __float_as_uint(f);
    return (u16)((u + 0x7FFF + ((u >> 16) & 1)) >> 16);
}
__device__ __forceinline__ float bf2f(u16 h) {
    return __uint_as_float((unsigned int)h << 16);
}

// ============ kA: F->Fb/FbT convert (2048) | W1->W1T (256) | hist partials (64) ====
__global__ __launch_bounds__(256) void kA(const float* __restrict__ F,
                                          const float* __restrict__ W1,
                                          const int* __restrict__ cats,
                                          u16* __restrict__ Fb,
                                          u16* __restrict__ FbT,
                                          u16* __restrict__ W1T,
                                          float* __restrict__ ws) {
    const int b = blockIdx.x;
    const int tid = threadIdx.x;
    __shared__ u16 T[64][72];
    __shared__ int h[16];

    if (b < 2048) {            // ---- convert + transpose F ----
        const int pb = b >> 2, fb = b & 3;
        const int p0 = pb * 64, f0 = fb * 64;
        {
            int p = tid >> 2, fq = tid & 3;
            const float* src = &F[(size_t)(p0 + p) * IN_F + f0 + fq * 16];
            u16x8 o0, o1;
            float4 v0 = *(const float4*)&src[0];
            float4 v1 = *(const float4*)&src[4];
            float4 v2 = *(const float4*)&src[8];
            float4 v3 = *(const float4*)&src[12];
            o0[0]=f2bf(v0.x); o0[1]=f2bf(v0.y); o0[2]=f2bf(v0.z); o0[3]=f2bf(v0.w);
            o0[4]=f2bf(v1.x); o0[5]=f2bf(v1.y); o0[6]=f2bf(v1.z); o0[7]=f2bf(v1.w);
            o1[0]=f2bf(v2.x); o1[1]=f2bf(v2.y); o1[2]=f2bf(v2.z); o1[3]=f2bf(v2.w);
            o1[4]=f2bf(v3.x); o1[5]=f2bf(v3.y); o1[6]=f2bf(v3.z); o1[7]=f2bf(v3.w);
            u16* dst = &Fb[(size_t)(p0 + p) * IN_F + f0 + fq * 16];
            *(u16x8*)dst = o0; *(u16x8*)&dst[8] = o1;
            *(u16x8*)&T[p][fq * 16] = o0; *(u16x8*)&T[p][fq * 16 + 8] = o1;
        }
        __syncthreads();
        {
            int f = tid >> 2, pq = tid & 3;
            u16x8 a0, a1;
#pragma unroll
            for (int m = 0; m < 8; m++) { a0[m] = T[pq*16 + m][f]; a1[m] = T[pq*16 + 8 + m][f]; }
            u16* dst = &FbT[(size_t)(f0 + f) * N_PTS + p0 + pq * 16];
            *(u16x8*)dst = a0; *(u16x8*)&dst[8] = a1;
        }
    } else if (b < 2304) {     // ---- W1 -> W1T bf16 ----
        const int bb = b - 2048;
        const int kb = bb & 3, jb = bb >> 2;
        {
            int kk = tid >> 2, j4 = (tid & 3) * 16;
            const float* src = &W1[(size_t)(kb * 64 + kk) * CF + jb * 64 + j4];
#pragma unroll
            for (int q = 0; q < 4; q++) {
                float4 v = *(const float4*)&src[q * 4];
                T[kk][j4 + q * 4 + 0] = f2bf(v.x); T[kk][j4 + q * 4 + 1] = f2bf(v.y);
                T[kk][j4 + q * 4 + 2] = f2bf(v.z); T[kk][j4 + q * 4 + 3] = f2bf(v.w);
            }
        }
        __syncthreads();
        {
            int jj = tid >> 2, ks = (tid & 3) * 16;
            int c = jb >> 2, n = (jb & 3) * 64 + jj;
            u16* dst = &W1T[((size_t)(c * 256 + n)) * 256 + kb * 64 + ks];
            u16x8 o0, o1;
#pragma unroll
            for (int m = 0; m < 8; m++) { o0[m] = T[ks + m][jj]; o1[m] = T[ks + 8 + m][jj]; }
            *(u16x8*)dst = o0;
            *(u16x8*)&dst[8] = o1;
        }
    } else {                   // ---- per-block category histogram (no atomics to ws) ----
        const int hb = b - 2304;      // 0..63
        if (tid < 16) h[tid] = 0;
        __syncthreads();
        const int n0 = hb * 512;
        atomicAdd(&h[cats[n0 + tid]], 1);
        atomicAdd(&h[cats[n0 + 256 + tid]], 1);
        __syncthreads();
        if (tid < 16) {
            u16* pc = (u16*)((int*)(ws + OFF_INT) + IO_PC);
            pc[hb * 16 + tid] = (u16)h[tid];
        }
    }
}

// ============ kB: Gram 128x128 tiles (3*nchunk) | column means (256) ============
// tile 0:(0,0) 1:(0,128) 2:(128,128); diag tiles stage A once (B=A).
__global__ __launch_bounds__(512) void kB(const u16* __restrict__ FbT,
                                          float* __restrict__ ws,
                                          int nchunk, int Kc) {
    const int tid = threadIdx.x;
    __shared__ __align__(16) u16 SA[2][8192];   // 2 x 16 KB (128 rows x 128 B)
    __shared__ __align__(16) u16 SB[2][8192];
    __shared__ float ps[8];

    if ((int)blockIdx.x < 3 * nchunk) {
        const int tile = blockIdx.x % 3, chunk = blockIdx.x / 3;
        const int i0 = (tile == 2) ? 128 : 0;
        const int j0 = (tile == 0) ? 0 : 128;
        const bool diag = (tile != 1);
        const int r0 = chunk * Kc;
        const int wv = tid >> 6, ln = tid & 63, g = ln >> 4, r16 = ln & 15;

        // staging coords: 2 instrs/thread/operand, flat = (wv*2+ss)*64+ln
        const int f0_ = (wv * 2 + 0) * 64 + ln, f1_ = (wv * 2 + 1) * 64 + ln;
        const int row0 = f0_ >> 3, u0 = f0_ & 7, k0off = ((u0 ^ (row0 & 7)) << 3);
        const int row1 = f1_ >> 3, u1 = f1_ & 7, k1off = ((u1 ^ (row1 & 7)) << 3);

        f32x4 acc8[8];
#pragma unroll
        for (int nt = 0; nt < 8; nt++)
#pragma unroll
            for (int i = 0; i < 4; i++) acc8[nt][i] = 0.f;

        const int nslab = Kc >> 6;
#define KB_STAGE(s, bf)                                                            \
        {   int p0s = r0 + (s) * 64;                                               \
            gload_lds16(FbT + (size_t)(i0 + row0) * N_PTS + p0s + k0off,           \
                        (char*)SA[bf] + (wv * 2 + 0) * 1024);                      \
            gload_lds16(FbT + (size_t)(i0 + row1) * N_PTS + p0s + k1off,           \
                        (char*)SA[bf] + (wv * 2 + 1) * 1024);                      \
            if (!diag) {                                                           \
                gload_lds16(FbT + (size_t)(j0 + row0) * N_PTS + p0s + k0off,       \
                            (char*)SB[bf] + (wv * 2 + 0) * 1024);                  \
                gload_lds16(FbT + (size_t)(j0 + row1) * N_PTS + p0s + k1off,       \
                            (char*)SB[bf] + (wv * 2 + 1) * 1024);                  \
            }                                                                      \
        }

        KB_STAGE(0, 0);
        __syncthreads();
        for (int s = 0; s < nslab; s++) {
            const int bf = s & 1;
            if (s + 1 < nslab) KB_STAGE(s + 1, bf ^ 1);
            const char* BB = diag ? (const char*)SA[bf] : (const char*)SB[bf];
#pragma unroll
            for (int ks = 0; ks < 2; ks++) {
                const int row = wv * 16 + r16;
                const int pha = ((ks * 4 + g) ^ (row & 7)) * 16;
                bf16x8 a = *(const bf16x8*)((const char*)SA[bf] + row * 128 + pha);
#pragma unroll
                for (int nt = 0; nt < 8; nt++) {
                    const int cr = nt * 16 + r16;
                    const int phb = ((ks * 4 + g) ^ (cr & 7)) * 16;
                    bf16x8 bb = *(const bf16x8*)(BB + cr * 128 + phb);
                    acc8[nt] = __builtin_amdgcn_mfma_f32_16x16x32_bf16(a, bb, acc8[nt], 0, 0, 0);
                }
            }
            __syncthreads();
        }
        float* Gp = ws + OFF_GP + (size_t)chunk * 49152 + tile * 16384;
#pragma unroll
        for (int nt = 0; nt < 8; nt++)
#pragma unroll
            for (int i = 0; i < 4; i++)
                Gp[(wv * 16 + g * 4 + i) * 128 + nt * 16 + r16] = acc8[nt][i];
    } else {
        // ---- column mean of FbT row ----
        const int row = blockIdx.x - 3 * nchunk;     // 0..255
        const u16* r = FbT + (size_t)row * N_PTS;
        float s = 0.f;
        for (int i = tid * 8; i < N_PTS; i += 4096) {
            u16x8 v = *(const u16x8*)&r[i];
#pragma unroll
            for (int m = 0; m < 8; m++) s += bf2f(v[m]);
        }
#pragma unroll
        for (int off = 32; off >= 1; off >>= 1) s += __shfl_xor(s, off);
        if ((tid & 63) == 0) ps[tid >> 6] = s;
        __syncthreads();
        if (tid == 0) {
            float t = 0.f;
#pragma unroll
            for (int w = 0; w < 8; w++) t += ps[w];
            ws[OFF_FBAR + row] = t * (1.0f / N_PTS);
        }
    }
}

// ============ kC: reduce Gram partials -> G (192) | deterministic scatter (64) ====
__global__ __launch_bounds__(256) void kC(const int* __restrict__ cats,
                                          float* __restrict__ ws, int nchunk) {
    const int tid = threadIdx.x;
    int* wi = (int*)(ws + OFF_INT);
    __shared__ int tot[16], bbs[16], coff[17], lh[16];

    if (blockIdx.x < 192) {
        const int e = blockIdx.x * 256 + tid;        // 0..49151
        const float* p = ws + OFF_GP + e;
        float s = 0.f;
        for (int c = 0; c < nchunk; c++) s += p[(size_t)c * 49152];
        const int t = e >> 14, x = (e >> 7) & 127, y = e & 127;
        const int a = ((t == 2) ? 128 : 0) + x;
        const int bcol = ((t == 0) ? 0 : 128) + y;
        ws[OFF_G + a * 256 + bcol] = s;
        ws[OFF_G + bcol * 256 + a] = s;
    } else {
        const int sb = blockIdx.x - 192;             // 0..63
        const u16* pc = (const u16*)(wi + IO_PC);
        if (tid < 16) {
            int T = 0, B = 0;
            for (int b2 = 0; b2 < 64; b2++) {
                int v = pc[b2 * 16 + tid];
                T += v;
                if (b2 < sb) B += v;
            }
            tot[tid] = T; bbs[tid] = B; lh[tid] = 0;
        }
        __syncthreads();
        if (tid == 0) {
            int co = 0;
            for (int c = 0; c < 16; c++) { coff[c] = co; co += tot[c]; }
            coff[16] = co;
        }
        __syncthreads();
        const int n0 = sb * 512;
        {
            int cA = cats[n0 + tid];
            int rA = atomicAdd(&lh[cA], 1);
            wi[IO_ORDER + coff[cA] + bbs[cA] + rA] = n0 + tid;
        }
        {
            int cB = cats[n0 + 256 + tid];
            int rB = atomicAdd(&lh[cB], 1);
            wi[IO_ORDER + coff[cB] + bbs[cB] + rB] = n0 + 256 + tid;
        }
        if (sb == 0 && tid < 17) wi[IO_CATOFF + tid] = coff[tid];
    }
}

// ============ kD: w^T G w split-b partials (128 colgrp x 8 b-splits) ============
__global__ __launch_bounds__(256) void k2b_stats(const float* __restrict__ W1,
                                                 const u16* __restrict__ W1T,
                                                 float* __restrict__ ws) {
    const int tid = threadIdx.x;
    const int jg = blockIdx.x >> 3, sp = blockIdx.x & 7;   // jg 0..127
    const int j0 = jg * 32;
    const int c = jg >> 3, n0 = (jg & 7) * 32;
    __shared__ float pwv[32][4], pwm[32][4];

    float acc[32];
#pragma unroll
    for (int jj = 0; jj < 32; jj++) acc[jj] = 0.f;

    const float* Gs = ws + OFF_G + (size_t)(sp * 32) * 256;
#pragma unroll 2
    for (int b = 0; b < 32; b++) {
        const float g = Gs[b * 256 + tid];
        const float* wrow = W1 + (size_t)(sp * 32 + b) * CF + j0;
#pragma unroll
        for (int jj = 0; jj < 32; jj++)
            acc[jj] += g * wrow[jj];
    }

    const int lane = tid & 63, wave = tid >> 6;
    const float fb = ws[OFF_FBAR + tid];
#pragma unroll
    for (int jj = 0; jj < 32; jj++) {
        const float wk = bf2f(W1T[((size_t)(c * 256 + n0 + jj)) * 256 + tid]);
        float v = wk * acc[jj];
#pragma unroll
        for (int off = 32; off >= 1; off >>= 1) v += __shfl_xor(v, off);
        if (lane == 0) pwv[jj][wave] = v;
        if (sp == 0) {
            float m = fb * wk;
#pragma unroll
            for (int off = 32; off >= 1; off >>= 1) m += __shfl_xor(m, off);
            if (lane == 0) pwm[jj][wave] = m;
        }
    }
    __syncthreads();
    if (tid < 32) {
        float v = pwv[tid][0] + pwv[tid][1] + pwv[tid][2] + pwv[tid][3];
        ws[OFF_VP + sp * 4096 + j0 + tid] = v;
        if (sp == 0) {
            float m = pwm[tid][0] + pwm[tid][1] + pwm[tid][2] + pwm[tid][3];
            ws[OFF_MU + j0 + tid] = m;
        }
    }
}

// ============ kE: combine partials -> scale/shift ============
__global__ __launch_bounds__(256) void k2c_finish(const float* __restrict__ gamma,
                                                  const float* __restrict__ beta,
                                                  float* __restrict__ ws) {
    const int j = blockIdx.x * 256 + threadIdx.x;   // 16 blocks -> 4096
    float v = 0.f;
#pragma unroll
    for (int sp = 0; sp < 8; sp++) v += ws[OFF_VP + sp * 4096 + j];
    const float mu = ws[OFF_MU + j];
    const float var = v * (1.0f / N_PTS) - mu * mu;
    const float sc = gamma[j] * rsqrtf(var + BN_EPS);
    ws[OFF_SCALE + j] = sc;
    ws[OFF_SHIFT + j] = beta[j] - mu * sc;
}

// ============ K5: bf16-MFMA GEMM (unchanged structure; tile info from CATOFF) ====
__global__ __launch_bounds__(512, 4) void k5_mfma(const u16* __restrict__ Fb,
                                                  const u16* __restrict__ W1T,
                                                  const float* __restrict__ Wc,
                                                  const float* __restrict__ bias,
                                                  const int* __restrict__ shifts,
                                                  const int* __restrict__ seg_lens,
                                                  const float* __restrict__ ws,
                                                  float* __restrict__ out) {
    const int* wi = (const int*)(ws + OFF_INT);
    const int t = blockIdx.x;
    int c = -1, base = 0, npts = 0;
    {
        int ts = 0;
#pragma unroll
        for (int cc = 0; cc < 16; cc++) {
            int o0 = wi[IO_CATOFF + cc], o1 = wi[IO_CATOFF + cc + 1];
            int cn = o1 - o0, ntl = (cn + 63) >> 6;
            if (c < 0 && t < ts + ntl) {
                int lt = t - ts;
                c = cc; base = o0 + lt * 64; npts = min(64, cn - lt * 64);
            }
            ts += ntl;
        }
    }
    if (c < 0) return;
    const int tid = threadIdx.x;
    const int wv = tid >> 6, ln = tid & 63;
    const int g = ln >> 4, r16 = ln & 15, r7 = r16 & 7;

    __shared__ __align__(16) u16 Fl[16384];     // 32 KB, [64 pt][32 units], ^(pt&7)
    __shared__ float red[64][8][8];             // 16 KB
    __shared__ int plds[64];

    if (tid < 64) plds[tid] = wi[IO_ORDER + base + min(tid, npts - 1)];
    const int col0 = wv * 32 + r16, col1 = col0 + 16;
    const float sc0 = ws[OFF_SCALE + c * 256 + col0];
    const float sc1 = ws[OFF_SCALE + c * 256 + col1];
    const float sh0 = ws[OFF_SHIFT + c * 256 + col0];
    const float sh1 = ws[OFF_SHIFT + c * 256 + col1];
    const float biasj = ((tid & 7) < 6) ? bias[tid & 7] : 0.f;
    const int shc = shifts[c], lnc = seg_lens[c];
    __syncthreads();                            // plds visible

#pragma unroll
    for (int s = 0; s < 4; s++) {
        int flat = (wv * 4 + s) * 64 + ln;
        int pt = flat >> 5, u = flat & 31;
        const u16* src = Fb + (size_t)plds[pt] * 256 + ((u ^ (pt & 7)) << 3);
        gload_lds16(src, (char*)Fl + (size_t)(wv * 4 + s) * 1024);
    }

    const u16* W1Tc = W1T + (size_t)c * 65536;
    const u16* wp0 = W1Tc + (size_t)col0 * 256 + g * 8;
    const u16* wp1 = W1Tc + (size_t)col1 * 256 + g * 8;

    __syncthreads();                            // F resident (vmcnt drained)

    f32x4 acc[4][2];
#pragma unroll
    for (int mt = 0; mt < 4; mt++)
#pragma unroll
        for (int nt = 0; nt < 2; nt++)
#pragma unroll
            for (int i = 0; i < 4; i++) acc[mt][nt][i] = 0.f;

    bf16x8 bf0[2], bf1[2];
    bf0[0] = *(const bf16x8*)(wp0);
    bf1[0] = *(const bf16x8*)(wp1);

#pragma unroll
    for (int kc = 0; kc < 8; kc++) {
        if (kc < 7) {
            bf0[(kc + 1) & 1] = *(const bf16x8*)(wp0 + (kc + 1) * 32);
            bf1[(kc + 1) & 1] = *(const bf16x8*)(wp1 + (kc + 1) * 32);
        }
#pragma unroll
        for (int mt = 0; mt < 4; mt++) {
            int row = mt * 16 + r16;
            int ph = ((kc * 4 + g) ^ r7) * 16;
            bf16x8 af = *(const bf16x8*)((const char*)Fl + (size_t)row * 512 + ph);
            acc[mt][0] = __builtin_amdgcn_mfma_f32_16x16x32_bf16(af, bf0[kc & 1], acc[mt][0], 0, 0, 0);
            acc[mt][1] = __builtin_amdgcn_mfma_f32_16x16x32_bf16(af, bf1[kc & 1], acc[mt][1], 0, 0, 0);
        }
    }
    __builtin_amdgcn_sched_barrier(0);

    float wc0[6], wc1[6];
#pragma unroll
    for (int s = 0; s < 6; s++) {
        wc0[s] = Wc[(size_t)c * 1536 + col0 * 6 + s];
        wc1[s] = Wc[(size_t)c * 1536 + col1 * 6 + s];
    }
#pragma unroll
    for (int mt = 0; mt < 4; mt++)
#pragma unroll
        for (int i = 0; i < 4; i++) {
            float x0 = acc[mt][0][i] * sc0 + sh0;  x0 = (x0 >= 0.f) ? x0 : 0.2f * x0;
            float x1 = acc[mt][1][i] * sc1 + sh1;  x1 = (x1 >= 0.f) ? x1 : 0.2f * x1;
            float pl[6];
#pragma unroll
            for (int s = 0; s < 6; s++) pl[s] = x0 * wc0[s] + x1 * wc1[s];
#pragma unroll
            for (int s = 0; s < 6; s++) {
                pl[s] += __shfl_xor(pl[s], 1);
                pl[s] += __shfl_xor(pl[s], 2);
                pl[s] += __shfl_xor(pl[s], 4);
                pl[s] += __shfl_xor(pl[s], 8);
            }
            if (r16 == 0) {
                int row = mt * 16 + g * 4 + i;
#pragma unroll
                for (int s = 0; s < 6; s++) red[row][wv][s] = pl[s];
            }
        }
    __syncthreads();

    {
        const int lpt = tid >> 3, j = tid & 7;
        float v = -1e30f;
        if (j < 6) {
            v = biasj;
#pragma unroll
            for (int w = 0; w < 8; w++) v += red[lpt][w][j];
        }
        float mx = v;
        mx = fmaxf(mx, __shfl_xor(mx, 1));
        mx = fmaxf(mx, __shfl_xor(mx, 2));
        mx = fmaxf(mx, __shfl_xor(mx, 4));
        float e = (j < 6) ? expf(v - mx) : 0.f;
        float se = e;
        se += __shfl_xor(se, 1);
        se += __shfl_xor(se, 2);
        se += __shfl_xor(se, 4);
        float lsm = v - (mx + logf(se));
        if (lpt < npts) {
            const int pid = plds[lpt];
            float* orow = out + (size_t)pid * OUTK;
            const int gb = ln & 56;
#pragma unroll
            for (int it = 0; it < 7; it++) {
                int k = j + it * 8;
                int jj = k - shc;
                int jc = min(max(jj, 0), 5);
                float val = __shfl(lsm, gb | jc);
                if (k < OUTK)
                    orow[k] = (jj >= 0 && jj < lnc) ? val : 0.f;
            }
        }
    }
}

extern "C" void kernel_launch(void* const* d_in, const int* in_sizes, int n_in,
                              void* d_out, int out_size, void* d_ws, size_t ws_size,
                              hipStream_t stream) {
    const float* F      = (const float*)d_in[0];
    const float* W1     = (const float*)d_in[1];
    const float* gamma  = (const float*)d_in[2];
    const float* beta   = (const float*)d_in[3];
    const float* Wc     = (const float*)d_in[4];
    const float* bias   = (const float*)d_in[5];
    const int*  cats    = (const int*)d_in[6];
    const int*  shifts  = (const int*)d_in[7];
    const int*  seglens = (const int*)d_in[8];
    float* out = (float*)d_out;
    float* ws  = (float*)d_ws;
    u16* Fb  = (u16*)(ws + OFF_FB);
    u16* FbT = (u16*)(ws + OFF_FBT);
    u16* W1T = (u16*)(ws + OFF_W1T);

    int nchunk = 64;
    if (ws_size < ((size_t)OFF_GP + 49152ull * 64) * 4) nchunk = 32;
    const int Kc = N_PTS / nchunk;

    hipLaunchKernelGGL(kA,         dim3(2368), dim3(256), 0, stream,
                       F, W1, cats, Fb, FbT, W1T, ws);
    hipLaunchKernelGGL(kB,         dim3(3 * nchunk + 256), dim3(512), 0, stream,
                       FbT, ws, nchunk, Kc);
    hipLaunchKernelGGL(kC,         dim3(256),  dim3(256), 0, stream, cats, ws, nchunk);
    hipLaunchKernelGGL(k2b_stats,  dim3(1024), dim3(256), 0, stream, W1, W1T, ws);
    hipLaunchKernelGGL(k2c_finish, dim3(16),   dim3(256), 0, stream, gamma, beta, ws);
    hipLaunchKernelGGL(k5_mfma,    dim3(528),  dim3(512), 0, stream,
                       Fb, W1T, Wc, bias, shifts, seglens, ws, out);
}

// Round 14
// 107.958 us; speedup vs baseline: 1.7365x; 1.1516x over previous
//
#include <hip/hip_runtime.h>
#include <hip/hip_bf16.h>
#include <math.h>

#define N_PTS 32768
#define IN_F  256
#define NUM_CAT 16
#define CF    4096
#define NSEG  6
#define OUTK  50
#define BN_EPS 1e-5f

typedef unsigned short u16;
typedef __attribute__((ext_vector_type(8))) short bf16x8;
typedef __attribute__((ext_vector_type(4))) float f32x4;
typedef __attribute__((ext_vector_type(4))) unsigned int u32x4;
typedef __attribute__((ext_vector_type(8))) unsigned short u16x8;

// ---- ws layout (float offsets) ----
#define OFF_G     0u          // 256*256
#define OFF_FBAR  65536u      // 256
#define OFF_SCALE 65792u      // 4096
#define OFF_SHIFT 69888u      // 4096
#define OFF_INT   73984u      // int region (33440 ints)
#define OFF_FB    107424u     // F bf16 [32768][256]
#define OFF_FBT   4301728u    // F^T bf16 [256][32768]
#define OFF_W1T   8496032u    // W1T bf16 [16][256 n][256 k]
#define OFF_GP    9020320u    // Gram partials [chunk][49152] (3 tiles x 128x128)
#define OFF_VP    OFF_GP              // 8 * 4096 floats
#define OFF_MU    (OFF_GP + 32768u)   // 4096 floats
#define IO_CATOFF 16          // 17 ints
#define IO_ORDER  67          // 32768 ints
#define IO_PC     32835       // u16[64][16] = 512 ints

__device__ __forceinline__ void gload_lds16(const void* g, void* l) {
    __builtin_amdgcn_global_load_lds(
        (const __attribute__((address_space(1))) void*)g,
        (__attribute__((address_space(3))) void*)l,
        16, 0, 0);
}
__device__ __forceinline__ u16 f2bf(float f) {
    unsigned int u = __float_as_uint(f);
    return (u16)((u + 0x7FFF + ((u >> 16) & 1)) >> 16);
}
__device__ __forceinline__ float bf2f(u16 h) {
    return __uint_as_float((unsigned int)h << 16);
}

// ============ kA: F->Fb/FbT convert (2048) | W1->W1T (256) | hist partials (64) ====
__global__ __launch_bounds__(256) void kA(const float* __restrict__ F,
                                          const float* __restrict__ W1,
                                          const int* __restrict__ cats,
                                          u16* __restrict__ Fb,
                                          u16* __restrict__ FbT,
                                          u16* __restrict__ W1T,
                                          float* __restrict__ ws) {
    const int b = blockIdx.x;
    const int tid = threadIdx.x;
    __shared__ u16 T[64][72];
    __shared__ int h[16];

    if (b < 2048) {
        const int pb = b >> 2, fb = b & 3;
        const int p0 = pb * 64, f0 = fb * 64;
        {
            int p = tid >> 2, fq = tid & 3;
            const float* src = &F[(size_t)(p0 + p) * IN_F + f0 + fq * 16];
            u16x8 o0, o1;
            float4 v0 = *(const float4*)&src[0];
            float4 v1 = *(const float4*)&src[4];
            float4 v2 = *(const float4*)&src[8];
            float4 v3 = *(const float4*)&src[12];
            o0[0]=f2bf(v0.x); o0[1]=f2bf(v0.y); o0[2]=f2bf(v0.z); o0[3]=f2bf(v0.w);
            o0[4]=f2bf(v1.x); o0[5]=f2bf(v1.y); o0[6]=f2bf(v1.z); o0[7]=f2bf(v1.w);
            o1[0]=f2bf(v2.x); o1[1]=f2bf(v2.y); o1[2]=f2bf(v2.z); o1[3]=f2bf(v2.w);
            o1[4]=f2bf(v3.x); o1[5]=f2bf(v3.y); o1[6]=f2bf(v3.z); o1[7]=f2bf(v3.w);
            u16* dst = &Fb[(size_t)(p0 + p) * IN_F + f0 + fq * 16];
            *(u16x8*)dst = o0; *(u16x8*)&dst[8] = o1;
            *(u16x8*)&T[p][fq * 16] = o0; *(u16x8*)&T[p][fq * 16 + 8] = o1;
        }
        __syncthreads();
        {
            int f = tid >> 2, pq = tid & 3;
            u16x8 a0, a1;
#pragma unroll
            for (int m = 0; m < 8; m++) { a0[m] = T[pq*16 + m][f]; a1[m] = T[pq*16 + 8 + m][f]; }
            u16* dst = &FbT[(size_t)(f0 + f) * N_PTS + p0 + pq * 16];
            *(u16x8*)dst = a0; *(u16x8*)&dst[8] = a1;
        }
    } else if (b < 2304) {
        const int bb = b - 2048;
        const int kb = bb & 3, jb = bb >> 2;
        {
            int kk = tid >> 2, j4 = (tid & 3) * 16;
            const float* src = &W1[(size_t)(kb * 64 + kk) * CF + jb * 64 + j4];
#pragma unroll
            for (int q = 0; q < 4; q++) {
                float4 v = *(const float4*)&src[q * 4];
                T[kk][j4 + q * 4 + 0] = f2bf(v.x); T[kk][j4 + q * 4 + 1] = f2bf(v.y);
                T[kk][j4 + q * 4 + 2] = f2bf(v.z); T[kk][j4 + q * 4 + 3] = f2bf(v.w);
            }
        }
        __syncthreads();
        {
            int jj = tid >> 2, ks = (tid & 3) * 16;
            int c = jb >> 2, n = (jb & 3) * 64 + jj;
            u16* dst = &W1T[((size_t)(c * 256 + n)) * 256 + kb * 64 + ks];
            u16x8 o0, o1;
#pragma unroll
            for (int m = 0; m < 8; m++) { o0[m] = T[ks + m][jj]; o1[m] = T[ks + 8 + m][jj]; }
            *(u16x8*)dst = o0;
            *(u16x8*)&dst[8] = o1;
        }
    } else {
        const int hb = b - 2304;
        if (tid < 16) h[tid] = 0;
        __syncthreads();
        const int n0 = hb * 512;
        atomicAdd(&h[cats[n0 + tid]], 1);
        atomicAdd(&h[cats[n0 + 256 + tid]], 1);
        __syncthreads();
        if (tid < 16) {
            u16* pc = (u16*)((int*)(ws + OFF_INT) + IO_PC);
            pc[hb * 16 + tid] = (u16)h[tid];
        }
    }
}

// ============ kB: Gram 128x128 tiles (3*nchunk) | column means (256) ============
__global__ __launch_bounds__(512) void kB(const u16* __restrict__ FbT,
                                          float* __restrict__ ws,
                                          int nchunk, int Kc) {
    const int tid = threadIdx.x;
    __shared__ __align__(16) u16 SA[2][8192];
    __shared__ __align__(16) u16 SB[2][8192];
    __shared__ float ps[8];

    if ((int)blockIdx.x < 3 * nchunk) {
        const int tile = blockIdx.x % 3, chunk = blockIdx.x / 3;
        const int i0 = (tile == 2) ? 128 : 0;
        const int j0 = (tile == 0) ? 0 : 128;
        const bool diag = (tile != 1);
        const int r0 = chunk * Kc;
        const int wv = tid >> 6, ln = tid & 63, g = ln >> 4, r16 = ln & 15;

        const int f0_ = (wv * 2 + 0) * 64 + ln, f1_ = (wv * 2 + 1) * 64 + ln;
        const int row0 = f0_ >> 3, u0 = f0_ & 7, k0off = ((u0 ^ (row0 & 7)) << 3);
        const int row1 = f1_ >> 3, u1 = f1_ & 7, k1off = ((u1 ^ (row1 & 7)) << 3);

        f32x4 acc8[8];
#pragma unroll
        for (int nt = 0; nt < 8; nt++)
#pragma unroll
            for (int i = 0; i < 4; i++) acc8[nt][i] = 0.f;

        const int nslab = Kc >> 6;
#define KB_STAGE(s, bf)                                                            \
        {   int p0s = r0 + (s) * 64;                                               \
            gload_lds16(FbT + (size_t)(i0 + row0) * N_PTS + p0s + k0off,           \
                        (char*)SA[bf] + (wv * 2 + 0) * 1024);                      \
            gload_lds16(FbT + (size_t)(i0 + row1) * N_PTS + p0s + k1off,           \
                        (char*)SA[bf] + (wv * 2 + 1) * 1024);                      \
            if (!diag) {                                                           \
                gload_lds16(FbT + (size_t)(j0 + row0) * N_PTS + p0s + k0off,       \
                            (char*)SB[bf] + (wv * 2 + 0) * 1024);                  \
                gload_lds16(FbT + (size_t)(j0 + row1) * N_PTS + p0s + k1off,       \
                            (char*)SB[bf] + (wv * 2 + 1) * 1024);                  \
            }                                                                      \
        }

        KB_STAGE(0, 0);
        __syncthreads();
        for (int s = 0; s < nslab; s++) {
            const int bf = s & 1;
            if (s + 1 < nslab) KB_STAGE(s + 1, bf ^ 1);
            const char* BB = diag ? (const char*)SA[bf] : (const char*)SB[bf];
#pragma unroll
            for (int ks = 0; ks < 2; ks++) {
                const int row = wv * 16 + r16;
                const int pha = ((ks * 4 + g) ^ (row & 7)) * 16;
                bf16x8 a = *(const bf16x8*)((const char*)SA[bf] + row * 128 + pha);
#pragma unroll
                for (int nt = 0; nt < 8; nt++) {
                    const int cr = nt * 16 + r16;
                    const int phb = ((ks * 4 + g) ^ (cr & 7)) * 16;
                    bf16x8 bb = *(const bf16x8*)(BB + cr * 128 + phb);
                    acc8[nt] = __builtin_amdgcn_mfma_f32_16x16x32_bf16(a, bb, acc8[nt], 0, 0, 0);
                }
            }
            __syncthreads();
        }
        float* Gp = ws + OFF_GP + (size_t)chunk * 49152 + tile * 16384;
#pragma unroll
        for (int nt = 0; nt < 8; nt++)
#pragma unroll
            for (int i = 0; i < 4; i++)
                Gp[(wv * 16 + g * 4 + i) * 128 + nt * 16 + r16] = acc8[nt][i];
    } else {
        const int row = blockIdx.x - 3 * nchunk;
        const u16* r = FbT + (size_t)row * N_PTS;
        float s = 0.f;
        for (int i = tid * 8; i < N_PTS; i += 4096) {
            u16x8 v = *(const u16x8*)&r[i];
#pragma unroll
            for (int m = 0; m < 8; m++) s += bf2f(v[m]);
        }
#pragma unroll
        for (int off = 32; off >= 1; off >>= 1) s += __shfl_xor(s, off);
        if ((tid & 63) == 0) ps[tid >> 6] = s;
        __syncthreads();
        if (tid == 0) {
            float t = 0.f;
#pragma unroll
            for (int w = 0; w < 8; w++) t += ps[w];
            ws[OFF_FBAR + row] = t * (1.0f / N_PTS);
        }
    }
}

// ============ kC: reduce Gram partials -> G (192) | deterministic scatter (64) ====
__global__ __launch_bounds__(256) void kC(const int* __restrict__ cats,
                                          float* __restrict__ ws, int nchunk) {
    const int tid = threadIdx.x;
    int* wi = (int*)(ws + OFF_INT);
    __shared__ int tot[16], bbs[16], coff[17], lh[16];

    if (blockIdx.x < 192) {
        const int e = blockIdx.x * 256 + tid;
        const float* p = ws + OFF_GP + e;
        float s = 0.f;
        for (int c = 0; c < nchunk; c++) s += p[(size_t)c * 49152];
        const int t = e >> 14, x = (e >> 7) & 127, y = e & 127;
        const int a = ((t == 2) ? 128 : 0) + x;
        const int bcol = ((t == 0) ? 0 : 128) + y;
        ws[OFF_G + a * 256 + bcol] = s;
        ws[OFF_G + bcol * 256 + a] = s;
    } else {
        const int sb = blockIdx.x - 192;
        const u16* pc = (const u16*)(wi + IO_PC);
        if (tid < 16) {
            int T = 0, B = 0;
            for (int b2 = 0; b2 < 64; b2++) {
                int v = pc[b2 * 16 + tid];
                T += v;
                if (b2 < sb) B += v;
            }
            tot[tid] = T; bbs[tid] = B; lh[tid] = 0;
        }
        __syncthreads();
        if (tid == 0) {
            int co = 0;
            for (int c = 0; c < 16; c++) { coff[c] = co; co += tot[c]; }
            coff[16] = co;
        }
        __syncthreads();
        const int n0 = sb * 512;
        {
            int cA = cats[n0 + tid];
            int rA = atomicAdd(&lh[cA], 1);
            wi[IO_ORDER + coff[cA] + bbs[cA] + rA] = n0 + tid;
        }
        {
            int cB = cats[n0 + 256 + tid];
            int rB = atomicAdd(&lh[cB], 1);
            wi[IO_ORDER + coff[cB] + bbs[cB] + rB] = n0 + 256 + tid;
        }
        if (sb == 0 && tid < 17) wi[IO_CATOFF + tid] = coff[tid];
    }
}

// ============ kD: w^T G w split-b partials (128 colgrp x 8 b-splits) ============
__global__ __launch_bounds__(256) void k2b_stats(const float* __restrict__ W1,
                                                 const u16* __restrict__ W1T,
                                                 float* __restrict__ ws) {
    const int tid = threadIdx.x;
    const int jg = blockIdx.x >> 3, sp = blockIdx.x & 7;
    const int j0 = jg * 32;
    const int c = jg >> 3, n0 = (jg & 7) * 32;
    __shared__ float pwv[32][4], pwm[32][4];

    float acc[32];
#pragma unroll
    for (int jj = 0; jj < 32; jj++) acc[jj] = 0.f;

    const float* Gs = ws + OFF_G + (size_t)(sp * 32) * 256;
#pragma unroll 2
    for (int b = 0; b < 32; b++) {
        const float g = Gs[b * 256 + tid];
        const float* wrow = W1 + (size_t)(sp * 32 + b) * CF + j0;
#pragma unroll
        for (int jj = 0; jj < 32; jj++)
            acc[jj] += g * wrow[jj];
    }

    const int lane = tid & 63, wave = tid >> 6;
    const float fb = ws[OFF_FBAR + tid];
#pragma unroll
    for (int jj = 0; jj < 32; jj++) {
        const float wk = bf2f(W1T[((size_t)(c * 256 + n0 + jj)) * 256 + tid]);
        float v = wk * acc[jj];
#pragma unroll
        for (int off = 32; off >= 1; off >>= 1) v += __shfl_xor(v, off);
        if (lane == 0) pwv[jj][wave] = v;
        if (sp == 0) {
            float m = fb * wk;
#pragma unroll
            for (int off = 32; off >= 1; off >>= 1) m += __shfl_xor(m, off);
            if (lane == 0) pwm[jj][wave] = m;
        }
    }
    __syncthreads();
    if (tid < 32) {
        float v = pwv[tid][0] + pwv[tid][1] + pwv[tid][2] + pwv[tid][3];
        ws[OFF_VP + sp * 4096 + j0 + tid] = v;
        if (sp == 0) {
            float m = pwm[tid][0] + pwm[tid][1] + pwm[tid][2] + pwm[tid][3];
            ws[OFF_MU + j0 + tid] = m;
        }
    }
}

// ============ kE: combine partials -> scale/shift ============
__global__ __launch_bounds__(256) void k2c_finish(const float* __restrict__ gamma,
                                                  const float* __restrict__ beta,
                                                  float* __restrict__ ws) {
    const int j = blockIdx.x * 256 + threadIdx.x;
    float v = 0.f;
#pragma unroll
    for (int sp = 0; sp < 8; sp++) v += ws[OFF_VP + sp * 4096 + j];
    const float mu = ws[OFF_MU + j];
    const float var = v * (1.0f / N_PTS) - mu * mu;
    const float sc = gamma[j] * rsqrtf(var + BN_EPS);
    ws[OFF_SCALE + j] = sc;
    ws[OFF_SHIFT + j] = beta[j] - mu * sc;
}

// ============ K5: bf16-MFMA GEMM — asm-pinned W registers + MFMA epilogue ============
// 64 pts x 256 cols, 512 thr / 8 waves. F tile in LDS (swizzled, staged once).
// W slice pinned in 64 VGPR via inline-asm global_load_dwordx4 (compiler cannot
// sink). Epilogue: BN+LeakyReLU -> X bf16 in LDS (reuses F tile) -> logits via
// 4 MFMAs/wave vs Wc B-fragment (replaces 384 shfl_xor). XCD-chunked block swizzle.
__global__ __launch_bounds__(512, 4) void k5_mfma(const u16* __restrict__ Fb,
                                                  const u16* __restrict__ W1T,
                                                  const float* __restrict__ Wc,
                                                  const float* __restrict__ bias,
                                                  const int* __restrict__ shifts,
                                                  const int* __restrict__ seg_lens,
                                                  const float* __restrict__ ws,
                                                  float* __restrict__ out) {
    const int* wi = (const int*)(ws + OFF_INT);
    const int bid = blockIdx.x;
    const int t = (bid & 7) * 66 + (bid >> 3);   // 528 = 8 x 66, bijective
    int c = -1, base = 0, npts = 0;
    {
        int ts = 0;
#pragma unroll
        for (int cc = 0; cc < 16; cc++) {
            int o0 = wi[IO_CATOFF + cc], o1 = wi[IO_CATOFF + cc + 1];
            int cn = o1 - o0, ntl = (cn + 63) >> 6;
            if (c < 0 && t < ts + ntl) {
                int lt = t - ts;
                c = cc; base = o0 + lt * 64; npts = min(64, cn - lt * 64);
            }
            ts += ntl;
        }
    }
    if (c < 0) return;
    const int tid = threadIdx.x;
    const int wv = tid >> 6, ln = tid & 63;
    const int g = ln >> 4, r16 = ln & 15, r7 = r16 & 7;

    __shared__ __align__(16) u16 Fl[16384];     // 32 KB: F tile, then X
    __shared__ float red[64][8][8];             // 16 KB
    __shared__ int plds[64];

    if (tid < 64) plds[tid] = wi[IO_ORDER + base + min(tid, npts - 1)];
    const int col0 = wv * 32 + r16, col1 = col0 + 16;
    const float sc0 = ws[OFF_SCALE + c * 256 + col0];
    const float sc1 = ws[OFF_SCALE + c * 256 + col1];
    const float sh0 = ws[OFF_SHIFT + c * 256 + col0];
    const float sh1 = ws[OFF_SHIFT + c * 256 + col1];
    const float biasj = ((tid & 7) < 6) ? bias[tid & 7] : 0.f;
    const int shc = shifts[c], lnc = seg_lens[c];

    // Wc B-fragment: lane holds B[k = wv*32 + g*8 + j][n = r16], n>=6 -> 0
    bf16x8 bwc;
#pragma unroll
    for (int j = 0; j < 8; j++) {
        float v = (r16 < 6) ? Wc[(size_t)c * 1536 + (wv * 32 + g * 8 + j) * 6 + r16] : 0.f;
        bwc[j] = (short)f2bf(v);
    }
    __syncthreads();                            // plds visible

    // ---- issue F staging ----
#pragma unroll
    for (int s = 0; s < 4; s++) {
        int flat = (wv * 4 + s) * 64 + ln;
        int pt = flat >> 5, u = flat & 31;
        const u16* src = Fb + (size_t)plds[pt] * 256 + ((u ^ (pt & 7)) << 3);
        gload_lds16(src, (char*)Fl + (size_t)(wv * 4 + s) * 1024);
    }

    // ---- asm-pinned W loads: 16 x 16B into 64 VGPRs, issued up-front ----
    const u16* W1Tc = W1T + (size_t)c * 65536;
    unsigned long long a0 = (unsigned long long)(W1Tc + (size_t)col0 * 256 + g * 8);
    unsigned long long a1 = (unsigned long long)(W1Tc + (size_t)col1 * 256 + g * 8);
    u32x4 wr[16];
#pragma unroll
    for (int kc = 0; kc < 8; kc++) {
        asm volatile("global_load_dwordx4 %0, %1, off offset:%2"
                     : "=v"(wr[kc * 2])     : "v"(a0), "i"(kc * 64));
        asm volatile("global_load_dwordx4 %0, %1, off offset:%2"
                     : "=v"(wr[kc * 2 + 1]) : "v"(a1), "i"(kc * 64));
    }

    __syncthreads();    // implicit s_waitcnt vmcnt(0): F staged AND all wr ready

    f32x4 acc[4][2];
#pragma unroll
    for (int mt = 0; mt < 4; mt++)
#pragma unroll
        for (int nt = 0; nt < 2; nt++)
#pragma unroll
            for (int i = 0; i < 4; i++) acc[mt][nt][i] = 0.f;

#pragma unroll
    for (int kc = 0; kc < 8; kc++) {
        bf16x8 b0 = __builtin_bit_cast(bf16x8, wr[kc * 2]);
        bf16x8 b1 = __builtin_bit_cast(bf16x8, wr[kc * 2 + 1]);
#pragma unroll
        for (int mt = 0; mt < 4; mt++) {
            int row = mt * 16 + r16;
            int ph = ((kc * 4 + g) ^ r7) * 16;
            bf16x8 af = *(const bf16x8*)((const char*)Fl + (size_t)row * 512 + ph);
            acc[mt][0] = __builtin_amdgcn_mfma_f32_16x16x32_bf16(af, b0, acc[mt][0], 0, 0, 0);
            acc[mt][1] = __builtin_amdgcn_mfma_f32_16x16x32_bf16(af, b1, acc[mt][1], 0, 0, 0);
        }
    }

    __syncthreads();    // all Fl reads done; safe to overwrite with X

    // ---- BN + LeakyReLU -> X bf16 into Fl (swizzled 16B units by row&7) ----
#pragma unroll
    for (int mt = 0; mt < 4; mt++)
#pragma unroll
        for (int i = 0; i < 4; i++) {
            const int row = mt * 16 + g * 4 + i;
            float x0 = acc[mt][0][i] * sc0 + sh0;  x0 = (x0 >= 0.f) ? x0 : 0.2f * x0;
            float x1 = acc[mt][1][i] * sc1 + sh1;  x1 = (x1 >= 0.f) ? x1 : 0.2f * x1;
            {   // col0 = wv*32 + r16  (unit wv*4 + (r16>>3))
                const int u = (col0 >> 3) ^ (row & 7);
                *(u16*)((char*)Fl + row * 512 + u * 16 + (col0 & 7) * 2) = f2bf(x0);
            }
            {   // col1 = col0 + 16
                const int u = (col1 >> 3) ^ (row & 7);
                *(u16*)((char*)Fl + row * 512 + u * 16 + (col1 & 7) * 2) = f2bf(x1);
            }
        }
    __syncthreads();

    // ---- logits partials via MFMA: X[64][256] (wave K-slice) x Wc[256][6] ----
    f32x4 zero = {0.f, 0.f, 0.f, 0.f};
#pragma unroll
    for (int mt = 0; mt < 4; mt++) {
        const int ar = mt * 16 + r16;           // A row (m = lane&15)
        const int au = (wv * 4 + g) ^ (ar & 7); // unit of k-slice wv*32+g*8
        bf16x8 ax = *(const bf16x8*)((const char*)Fl + ar * 512 + au * 16);
        f32x4 pc = __builtin_amdgcn_mfma_f32_16x16x32_bf16(ax, bwc, zero, 0, 0, 0);
        if (r16 < 8) {
#pragma unroll
            for (int i = 0; i < 4; i++)
                red[mt * 16 + g * 4 + i][wv][r16] = pc[i];
        }
    }
    __syncthreads();

    // ---- finalize: 64 pts x 8 lanes ----
    {
        const int lpt = tid >> 3, j = tid & 7;
        float v = -1e30f;
        if (j < 6) {
            v = biasj;
#pragma unroll
            for (int w = 0; w < 8; w++) v += red[lpt][w][j];
        }
        float mx = v;
        mx = fmaxf(mx, __shfl_xor(mx, 1));
        mx = fmaxf(mx, __shfl_xor(mx, 2));
        mx = fmaxf(mx, __shfl_xor(mx, 4));
        float e = (j < 6) ? expf(v - mx) : 0.f;
        float se = e;
        se += __shfl_xor(se, 1);
        se += __shfl_xor(se, 2);
        se += __shfl_xor(se, 4);
        float lsm = v - (mx + logf(se));
        if (lpt < npts) {
            const int pid = plds[lpt];
            float* orow = out + (size_t)pid * OUTK;
            const int gb = ln & 56;
#pragma unroll
            for (int it = 0; it < 7; it++) {
                int k = j + it * 8;
                int jj = k - shc;
                int jc = min(max(jj, 0), 5);
                float val = __shfl(lsm, gb | jc);
                if (k < OUTK)
                    orow[k] = (jj >= 0 && jj < lnc) ? val : 0.f;
            }
        }
    }
}

extern "C" void kernel_launch(void* const* d_in, const int* in_sizes, int n_in,
                              void* d_out, int out_size, void* d_ws, size_t ws_size,
                              hipStream_t stream) {
    const float* F      = (const float*)d_in[0];
    const float* W1     = (const float*)d_in[1];
    const float* gamma  = (const float*)d_in[2];
    const float* beta   = (const float*)d_in[3];
    const float* Wc     = (const float*)d_in[4];
    const float* bias   = (const float*)d_in[5];
    const int*  cats    = (const int*)d_in[6];
    const int*  shifts  = (const int*)d_in[7];
    const int*  seglens = (const int*)d_in[8];
    float* out = (float*)d_out;
    float* ws  = (float*)d_ws;
    u16* Fb  = (u16*)(ws + OFF_FB);
    u16* FbT = (u16*)(ws + OFF_FBT);
    u16* W1T = (u16*)(ws + OFF_W1T);

    int nchunk = 64;
    if (ws_size < ((size_t)OFF_GP + 49152ull * 64) * 4) nchunk = 32;
    const int Kc = N_PTS / nchunk;

    hipLaunchKernelGGL(kA,         dim3(2368), dim3(256), 0, stream,
                       F, W1, cats, Fb, FbT, W1T, ws);
    hipLaunchKernelGGL(kB,         dim3(3 * nchunk + 256), dim3(512), 0, stream,
                       FbT, ws, nchunk, Kc);
    hipLaunchKernelGGL(kC,         dim3(256),  dim3(256), 0, stream, cats, ws, nchunk);
    hipLaunchKernelGGL(k2b_stats,  dim3(1024), dim3(256), 0, stream, W1, W1T, ws);
    hipLaunchKernelGGL(k2c_finish, dim3(16),   dim3(256), 0, stream, gamma, beta, ws);
    hipLaunchKernelGGL(k5_mfma,    dim3(528),  dim3(512), 0, stream,
                       Fb, W1T, Wc, bias, shifts, seglens, ws, out);
}